// Round 6
// baseline (357.096 us; speedup 1.0000x reference)
//
#include <hip/hip_runtime.h>
#include <hip/hip_bf16.h>

#define N_NODES 61440
#define NEDGE   491520
#define BATCH   2048
#define TT      30
#define C1      128
#define C2      512
#define C3      128
#define FCK     3840   // 128*30
#define MAXDEG  40     // Poisson(8) tail: P(deg>40) ~ 1e-11

typedef float floatx16 __attribute__((ext_vector_type(16)));
typedef __bf16 bfrag   __attribute__((ext_vector_type(8)));

static __device__ __forceinline__ unsigned short f2bf(float f) {
    unsigned u = __float_as_uint(f);
    u = u + 0x7fffu + ((u >> 16) & 1u);
    return (unsigned short)(u >> 16);
}
static __device__ __forceinline__ bfrag ldf(const void* p) { return *(const bfrag*)p; }
#define MFMA(a, b, c) __builtin_amdgcn_mfma_f32_32x32x16_bf16(a, b, c, 0, 0, 0)

// ---------------------------------------------------------------- GCN part

__global__ void k_zero(int* __restrict__ cnt) {
    int i = blockIdx.x * blockDim.x + threadIdx.x;
    if (i < N_NODES) cnt[i] = 0;
}

// Bucket src by dst; eidx transposed [slot][node] so gather reads coalesce.
__global__ void k_edges(const int* __restrict__ e32, int* __restrict__ cnt,
                        int* __restrict__ eidx) {
    int i = blockIdx.x * blockDim.x + threadIdx.x;
    if (i >= NEDGE) return;
    bool is64 = (e32[1] == 0) & (e32[3] == 0) & (e32[5] == 0) & (e32[7] == 0);
    int s, d;
    if (is64) { s = e32[2 * i]; d = e32[2 * (NEDGE + i)]; }
    else      { s = e32[i];     d = e32[NEDGE + i]; }
    int slot = atomicAdd(&cnt[d], 1);
    if (slot < MAXDEG) eidx[slot * N_NODES + d] = s;
}

__global__ void k_hdinv(const float* __restrict__ x, const float* __restrict__ gw,
                        const float* __restrict__ gb, const int* __restrict__ cnt,
                        float* __restrict__ dinv, float* __restrict__ hd,
                        float* __restrict__ g) {
    int i = blockIdx.x * blockDim.x + threadIdx.x;
    if (i >= N_NODES) return;
    float di = rsqrtf(1.0f + (float)cnt[i]);
    dinv[i] = di;
    float xi[12];
    const float4* xp = (const float4*)(x + i * 12);
    float4 a = xp[0], b4 = xp[1], c4 = xp[2];
    xi[0]=a.x; xi[1]=a.y; xi[2]=a.z; xi[3]=a.w;
    xi[4]=b4.x; xi[5]=b4.y; xi[6]=b4.z; xi[7]=b4.w;
    xi[8]=c4.x; xi[9]=c4.y; xi[10]=c4.z; xi[11]=c4.w;
    float d2 = di * di;
    #pragma unroll
    for (int c = 0; c < 12; c++) {
        float acc = 0.f;
        #pragma unroll
        for (int j = 0; j < 12; j++) acc += xi[j] * gw[c * 12 + j];
        hd[i * 12 + c] = di * acc;
        g[i * 12 + c] = d2 * acc + gb[c];
    }
}

// 3 threads per node, 4 channels each (720 blocks: better occupancy).
__global__ void k_gather(const int* __restrict__ cnt, const int* __restrict__ eidx,
                         const float* __restrict__ dinv, const float* __restrict__ hd,
                         float* __restrict__ g) {
    int part = blockIdx.x / 240;
    int d = (blockIdx.x - part * 240) * 256 + threadIdx.x;
    int n = cnt[d];
    if (n > MAXDEG) n = MAXDEG;
    float4 a = make_float4(0.f, 0.f, 0.f, 0.f);
    for (int j = 0; j < n; j++) {
        int s = eidx[j * N_NODES + d];           // coalesced across lanes
        float4 h = *(const float4*)(hd + (size_t)s * 12 + part * 4);
        a.x += h.x; a.y += h.y; a.z += h.z; a.w += h.w;
    }
    float di = dinv[d];
    float4* gp = (float4*)(g + (size_t)d * 12) + part;
    float4 gv = *gp;
    gv.x += di * a.x; gv.y += di * a.y; gv.z += di * a.z; gv.w += di * a.w;
    *gp = gv;
}

// ------------------------------------------------------- weight repacking
__global__ void k_repack(const float* __restrict__ cw0, const float* __restrict__ dw0,
                         const float* __restrict__ cw1, const float* __restrict__ dw1,
                         const float* __restrict__ cw2, const float* __restrict__ dw2,
                         const float* __restrict__ fcw,
                         float* __restrict__ w0T, float* __restrict__ d0T,
                         unsigned short* __restrict__ W1f, unsigned short* __restrict__ D1f,
                         unsigned short* __restrict__ W2f, unsigned short* __restrict__ D2f,
                         unsigned short* __restrict__ FCWf) {
    int i = blockIdx.x * blockDim.x + threadIdx.x;
    if (i < 36 * 128) { int oc = i & 127, r = i >> 7; w0T[i] = cw0[oc * 36 + r]; }
    if (i < 12 * 128) { int oc = i & 127, ic = i >> 7; d0T[i] = dw0[oc * 12 + ic]; }
    if (i < 196608) {                       // W1f
        int pos = i & 511, f = i >> 9;
        int lane = pos >> 3, e = pos & 7;
        int oct = f & 15, q = (f >> 4) & 7, tap = f >> 7;
        int oc = oct * 32 + (lane & 31), ic = q * 16 + (lane >> 5) * 8 + e;
        W1f[i] = f2bf(cw1[(oc * 128 + ic) * 3 + tap]);
    } else if (i < 262144) {                // D1f
        int j = i - 196608;
        int pos = j & 511, f = j >> 9;
        int lane = pos >> 3, e = pos & 7;
        int oct = f & 15, q = f >> 4;
        int oc = oct * 32 + (lane & 31), ic = q * 16 + (lane >> 5) * 8 + e;
        D1f[j] = f2bf(dw1[oc * 128 + ic]);
    } else if (i < 458752) {                // W2f
        int j = i - 262144;
        int pos = j & 511, f = j >> 9;
        int lane = pos >> 3, e = pos & 7;
        int oct = f & 3, q = (f >> 2) & 31, tap = f >> 7;
        int oc = oct * 32 + (lane & 31), ic = q * 16 + (lane >> 5) * 8 + e;
        W2f[j] = f2bf(cw2[(oc * 512 + ic) * 3 + tap]);
    } else if (i < 524288) {                // D2f
        int j = i - 458752;
        int pos = j & 511, f = j >> 9;
        int lane = pos >> 3, e = pos & 7;
        int oct = f & 3, q = f >> 2;
        int oc = oct * 32 + (lane & 31), ic = q * 16 + (lane >> 5) * 8 + e;
        D2f[j] = f2bf(dw2[oc * 512 + ic]);
    } else if (i < 892928) {                // FCWf (240*3 frags)
        int j = i - 524288;
        int pos = j & 511, f = j >> 9;
        int lane = pos >> 3, e = pos & 7;
        int oct = f % 3, q = f / 3;
        int o = oct * 32 + (lane & 31);
        int k = q * 16 + (lane >> 5) * 8 + e;
        float v = (o < 72) ? fcw[o * 3840 + (k & 127) * 30 + (k >> 7)] : 0.f;
        FCWf[j] = f2bf(v);
    }
}

// ------------------------------------------------------------ TCN block 0
// 12 -> 128, k=3 dil=1, + 1x1 down. 4 batch/WG (512 WGs -> 2/CU).
__global__ __launch_bounds__(256) void k_block0(
        const float* __restrict__ g, const float* __restrict__ w0T,
        const float* __restrict__ d0T, const float* __restrict__ cb0,
        const float* __restrict__ db0, unsigned short* __restrict__ X1b) {
    __shared__ float wl[36 * 128];
    __shared__ float dl[12 * 128];
    __shared__ float cbl[128], dbl[128];
    __shared__ float x0[4 * TT * 12];
    __shared__ __align__(16) unsigned short st[2][TT * 136];
    int tid = threadIdx.x;
    int b0 = blockIdx.x * 4;
    for (int i = tid; i < 36 * 128; i += 256) wl[i] = w0T[i];
    for (int i = tid; i < 12 * 128; i += 256) dl[i] = d0T[i];
    if (tid < 128) { cbl[tid] = cb0[tid]; dbl[tid] = db0[tid]; }
    for (int i = tid; i < 4 * TT * 12; i += 256) x0[i] = g[b0 * TT * 12 + i];
    __syncthreads();
    int oc = tid & 127, half = tid >> 7;
    float cb = cbl[oc], db = dbl[oc];
    for (int bi = 0; bi < 2; bi++) {
        int bl = bi * 2 + half;
        const float* xb = x0 + bl * (TT * 12);
        float conv[TT], res[TT];
        #pragma unroll
        for (int t = 0; t < TT; t++) { conv[t] = 0.f; res[t] = 0.f; }
        #pragma unroll
        for (int ic = 0; ic < 12; ic++) {
            float w0v = wl[(ic * 3 + 0) * 128 + oc];
            float w1v = wl[(ic * 3 + 1) * 128 + oc];
            float w2v = wl[(ic * 3 + 2) * 128 + oc];
            float dv  = dl[ic * 128 + oc];
            #pragma unroll
            for (int t = 0; t < TT; t++) {
                float xv = xb[t * 12 + ic];
                conv[t] += w2v * xv;
                if (t + 1 < TT) conv[t + 1] += w1v * xv;
                if (t + 2 < TT) conv[t + 2] += w0v * xv;
                res[t] += dv * xv;
            }
        }
        #pragma unroll
        for (int t = 0; t < TT; t++) {
            float o1 = fmaxf(conv[t] + cb, 0.f);
            st[half][t * 136 + oc] = f2bf(fmaxf(o1 + res[t] + db, 0.f));
        }
        __syncthreads();
        for (int idx = tid; idx < 2 * TT * 16; idx += 256) {
            int h = idx / (TT * 16), rem = idx - h * (TT * 16);
            int row = rem >> 4, seg = rem & 15;
            *(uint4*)(X1b + (size_t)((b0 + bi * 2 + h) * TT + row) * 128 + seg * 8) =
                *(const uint4*)(&st[h][row * 136 + seg * 8]);
        }
        __syncthreads();
    }
}

// -------------------------------------------------- TCN blocks 1+2, MFMA
// 512 threads (8 waves), 2 batch/WG, 80 KB LDS -> 2 WG/CU = 4 waves/SIMD.
// Per-wave work halved vs 4-wave version; no weight double-buffer (TLP
// hides L2 latency; launch_bounds(512,4) forces <=128 regs for 2 WG/CU).
__global__ __launch_bounds__(512, 4) void k_tcn12(
        const unsigned short* __restrict__ X1b,
        const unsigned short* __restrict__ W1f, const unsigned short* __restrict__ D1f,
        const float* __restrict__ cb1, const float* __restrict__ db1,
        const unsigned short* __restrict__ W2f, const unsigned short* __restrict__ D2f,
        const float* __restrict__ cb2, const float* __restrict__ db2,
        unsigned short* __restrict__ X3b) {
    __shared__ __align__(16) unsigned short X1l[61 * 136];  // rows 0..59 data, 60 = zeros
    __shared__ __align__(16) unsigned short X2l[61 * 520];
    const int tid  = threadIdx.x;
    const int lane = tid & 63;
    const int wave = tid >> 6;      // 0..7
    const int tcol = lane & 31;
    const int half = lane >> 5;
    const int b0 = blockIdx.x * 2;

    for (int idx = tid; idx < 960; idx += 512) {
        int row = idx >> 4, seg = idx & 15;
        *(uint4*)(X1l + row * 136 + seg * 8) =
            *(const uint4*)(X1b + ((size_t)(b0 * 30 + row) << 7) + seg * 8);
    }
    if (tid < 17) *(uint4*)(X1l + 60 * 136 + tid * 8) = make_uint4(0, 0, 0, 0);
    if (tid < 65) *(uint4*)(X2l + 60 * 520 + tid * 8) = make_uint4(0, 0, 0, 0);
    __syncthreads();

    // ---- phase 1: block1 (128->512, k=3 dil=3) + 1x1 down  -> X2l (bf16)
    // 32 units (16 oct x 2 bl) over 8 waves, 4 serial units each.
    for (int i = 0; i < 4; i++) {
        int u = i * 8 + wave;
        int oct = u & 15;
        int bl = u >> 4;
        floatx16 accc = 0, accd = 0;
        #pragma unroll
        for (int qc = 0; qc < 2; qc++) {
            bfrag aw[12], ad[4];
            #pragma unroll
            for (int tap = 0; tap < 3; tap++)
                #pragma unroll
                for (int qq = 0; qq < 4; qq++)
                    aw[tap * 4 + qq] =
                        ldf(W1f + (((tap * 8 + qc * 4 + qq) * 16 + oct) << 9) + lane * 8);
            #pragma unroll
            for (int qq = 0; qq < 4; qq++)
                ad[qq] = ldf(D1f + (((qc * 4 + qq) * 16 + oct) << 9) + lane * 8);
            bfrag bx[3][4];
            #pragma unroll
            for (int si = 0; si < 3; si++) {
                int trow = tcol - si * 3;
                const unsigned short* rp = ((unsigned)trow < 30u)
                    ? (X1l + (bl * 30 + trow) * 136) : (X1l + 60 * 136);
                #pragma unroll
                for (int qq = 0; qq < 4; qq++)
                    bx[si][qq] = ldf(rp + (qc * 4 + qq) * 16 + half * 8);
            }
            #pragma unroll
            for (int qq = 0; qq < 4; qq++) {
                accc = MFMA(aw[8 + qq], bx[0][qq], accc);
                accc = MFMA(aw[4 + qq], bx[1][qq], accc);
                accc = MFMA(aw[qq],     bx[2][qq], accc);
                accd = MFMA(ad[qq],     bx[0][qq], accd);
            }
        }
        if (tcol < 30) {
            unsigned short* wp = X2l + (bl * 30 + tcol) * 520 + oct * 32 + half * 4;
            #pragma unroll
            for (int gi = 0; gi < 4; gi++) {
                int ocb = oct * 32 + half * 4 + gi * 8;
                float4 cbv = *(const float4*)(cb1 + ocb);
                float4 dbv = *(const float4*)(db1 + ocb);
                float v0 = fmaxf(fmaxf(accc[gi*4+0] + cbv.x, 0.f) + accd[gi*4+0] + dbv.x, 0.f);
                float v1 = fmaxf(fmaxf(accc[gi*4+1] + cbv.y, 0.f) + accd[gi*4+1] + dbv.y, 0.f);
                float v2 = fmaxf(fmaxf(accc[gi*4+2] + cbv.z, 0.f) + accd[gi*4+2] + dbv.z, 0.f);
                float v3 = fmaxf(fmaxf(accc[gi*4+3] + cbv.w, 0.f) + accd[gi*4+3] + dbv.w, 0.f);
                unsigned p0 = (unsigned)f2bf(v0) | ((unsigned)f2bf(v1) << 16);
                unsigned p1 = (unsigned)f2bf(v2) | ((unsigned)f2bf(v3) << 16);
                *(uint2*)(wp + gi * 8) = make_uint2(p0, p1);
            }
        }
    }
    __syncthreads();

    // ---- phase 2: block2 (512->128, k=3 dil=9) + 1x1 down -> staged X3
    // 8 units (4 oct x 2 bl) over 8 waves, 1 each.
    {
        const int oct = wave >> 1;
        const int bl = wave & 1;
        floatx16 accc = 0, accd = 0;
        for (int qc = 0; qc < 8; qc++) {
            bfrag aw[12], ad[4];
            #pragma unroll
            for (int tap = 0; tap < 3; tap++)
                #pragma unroll
                for (int qq = 0; qq < 4; qq++)
                    aw[tap * 4 + qq] =
                        ldf(W2f + (((tap * 32 + qc * 4 + qq) * 4 + oct) << 9) + lane * 8);
            #pragma unroll
            for (int qq = 0; qq < 4; qq++)
                ad[qq] = ldf(D2f + (((qc * 4 + qq) * 4 + oct) << 9) + lane * 8);
            bfrag bx[3][4];
            #pragma unroll
            for (int si = 0; si < 3; si++) {
                int trow = tcol - si * 9;
                const unsigned short* rp = ((unsigned)trow < 30u)
                    ? (X2l + (bl * 30 + trow) * 520) : (X2l + 60 * 520);
                #pragma unroll
                for (int qq = 0; qq < 4; qq++)
                    bx[si][qq] = ldf(rp + (qc * 4 + qq) * 16 + half * 8);
            }
            #pragma unroll
            for (int qq = 0; qq < 4; qq++) {
                accc = MFMA(aw[8 + qq], bx[0][qq], accc);
                accc = MFMA(aw[4 + qq], bx[1][qq], accc);
                accc = MFMA(aw[qq],     bx[2][qq], accc);
                accd = MFMA(ad[qq],     bx[0][qq], accd);
            }
        }
        if (tcol < 30) {   // stage into X1l area (free after phase 1)
            unsigned short* wp = X1l + (bl * 30 + tcol) * 136 + oct * 32 + half * 4;
            #pragma unroll
            for (int gi = 0; gi < 4; gi++) {
                int ocb = oct * 32 + half * 4 + gi * 8;
                float4 cbv = *(const float4*)(cb2 + ocb);
                float4 dbv = *(const float4*)(db2 + ocb);
                float v0 = fmaxf(fmaxf(accc[gi*4+0] + cbv.x, 0.f) + accd[gi*4+0] + dbv.x, 0.f);
                float v1 = fmaxf(fmaxf(accc[gi*4+1] + cbv.y, 0.f) + accd[gi*4+1] + dbv.y, 0.f);
                float v2 = fmaxf(fmaxf(accc[gi*4+2] + cbv.z, 0.f) + accd[gi*4+2] + dbv.z, 0.f);
                float v3 = fmaxf(fmaxf(accc[gi*4+3] + cbv.w, 0.f) + accd[gi*4+3] + dbv.w, 0.f);
                unsigned p0 = (unsigned)f2bf(v0) | ((unsigned)f2bf(v1) << 16);
                unsigned p1 = (unsigned)f2bf(v2) | ((unsigned)f2bf(v3) << 16);
                *(uint2*)(wp + gi * 8) = make_uint2(p0, p1);
            }
        }
    }
    __syncthreads();
    // coalesced flush: 60 rows x 256 B contiguous
    for (int idx = tid; idx < 960; idx += 512) {
        int row = idx >> 4, seg = idx & 15;
        *(uint4*)(X3b + ((size_t)(b0 * 30 + row) << 7) + seg * 8) =
            *(const uint4*)(X1l + row * 136 + seg * 8);
    }
}

// ------------------------------------------------------------- FC (MFMA)
// P layout [kc][o(96)][b(2048)] for fully coalesced stores/reads.
__global__ __launch_bounds__(256) void k_fc_mfma(
        const unsigned short* __restrict__ X3b,
        const unsigned short* __restrict__ FCWf,
        float* __restrict__ P) {
    const int tid  = threadIdx.x;
    const int lane = tid & 63;
    const int wave = tid >> 6;
    const int half = lane >> 5;
    const int bg = blockIdx.x & 15;
    const int kc = blockIdx.x >> 4;
    const int b = bg * 128 + wave * 32 + (lane & 31);

    floatx16 acc[3];
    acc[0] = 0; acc[1] = 0; acc[2] = 0;
    #pragma unroll
    for (int ql = 0; ql < 15; ql++) {
        int q = kc * 15 + ql;
        bfrag bx = ldf(X3b + (size_t)b * FCK + q * 16 + half * 8);
        #pragma unroll
        for (int oct = 0; oct < 3; oct++) {
            bfrag af = ldf(FCWf + ((q * 3 + oct) << 9) + lane * 8);
            acc[oct] = MFMA(af, bx, acc[oct]);
        }
    }
    float* base = P + (size_t)kc * 96 * BATCH;
    #pragma unroll
    for (int oct = 0; oct < 3; oct++)
        #pragma unroll
        for (int j = 0; j < 16; j++) {
            int o = oct * 32 + half * 4 + (j >> 2) * 8 + (j & 3);
            base[(size_t)o * BATCH + b] = acc[oct][j];
        }
}

__global__ __launch_bounds__(256) void k_fc_reduce(
        const float* __restrict__ P, const float* __restrict__ fcb,
        float* __restrict__ out) {
    int j = blockIdx.x * blockDim.x + threadIdx.x;   // j = o*2048 + b, o<72
    int o = j >> 11, b = j & 2047;
    float acc = fcb[o];
    #pragma unroll
    for (int kc = 0; kc < 16; kc++)
        acc += P[((size_t)kc * 96 + o) * BATCH + b];
    out[b * 72 + o] = acc;
}

// ---------------------------------------------------------------- launch

extern "C" void kernel_launch(void* const* d_in, const int* in_sizes, int n_in,
                              void* d_out, int out_size, void* d_ws, size_t ws_size,
                              hipStream_t stream) {
    const float* x   = (const float*)d_in[0];
    const int*   e32 = (const int*)  d_in[1];
    const float* gw  = (const float*)d_in[2];
    const float* gb  = (const float*)d_in[3];
    const float* cw0 = (const float*)d_in[4];
    const float* cb0 = (const float*)d_in[5];
    const float* dw0 = (const float*)d_in[6];
    const float* db0 = (const float*)d_in[7];
    const float* cw1 = (const float*)d_in[8];
    const float* cb1 = (const float*)d_in[9];
    const float* dw1 = (const float*)d_in[10];
    const float* db1 = (const float*)d_in[11];
    const float* cw2 = (const float*)d_in[12];
    const float* cb2 = (const float*)d_in[13];
    const float* dw2 = (const float*)d_in[14];
    const float* db2 = (const float*)d_in[15];
    const float* fcw = (const float*)d_in[16];
    const float* fcb = (const float*)d_in[17];

    char* w = (char*)d_ws;
    auto alloc = [&](size_t bytes) {
        char* p = w;
        w += (bytes + 255) & ~(size_t)255;
        return p;
    };
    int*   cnt  = (int*)  alloc(N_NODES * 4);
    int*   eidx = (int*)  alloc((size_t)N_NODES * MAXDEG * 4);
    float* dinv = (float*)alloc(N_NODES * 4);
    float* hd   = (float*)alloc((size_t)N_NODES * 12 * 4);
    float* g    = (float*)alloc((size_t)N_NODES * 12 * 4);
    float* w0T  = (float*)alloc(36 * 128 * 4);
    float* d0T  = (float*)alloc(12 * 128 * 4);
    unsigned short* W1f  = (unsigned short*)alloc(196608 * 2);
    unsigned short* D1f  = (unsigned short*)alloc(65536 * 2);
    unsigned short* W2f  = (unsigned short*)alloc(196608 * 2);
    unsigned short* D2f  = (unsigned short*)alloc(65536 * 2);
    unsigned short* FCWf = (unsigned short*)alloc(368640 * 2);
    unsigned short* X1b  = (unsigned short*)alloc((size_t)BATCH * TT * C1 * 2);
    unsigned short* X3b  = (unsigned short*)alloc((size_t)BATCH * TT * C3 * 2);
    float* P    = (float*)alloc((size_t)16 * 96 * BATCH * 4);

    k_zero<<<N_NODES / 256, 256, 0, stream>>>(cnt);
    k_edges<<<NEDGE / 256, 256, 0, stream>>>(e32, cnt, eidx);
    k_hdinv<<<N_NODES / 256, 256, 0, stream>>>(x, gw, gb, cnt, dinv, hd, g);
    k_gather<<<720, 256, 0, stream>>>(cnt, eidx, dinv, hd, g);
    k_repack<<<(892928 + 255) / 256, 256, 0, stream>>>(
        cw0, dw0, cw1, dw1, cw2, dw2, fcw, w0T, d0T, W1f, D1f, W2f, D2f, FCWf);
    k_block0<<<BATCH / 4, 256, 0, stream>>>(g, w0T, d0T, cb0, db0, X1b);
    k_tcn12<<<BATCH / 2, 512, 0, stream>>>(X1b, W1f, D1f, cb1, db1,
                                           W2f, D2f, cb2, db2, X3b);
    k_fc_mfma<<<256, 256, 0, stream>>>(X3b, FCWf, P);
    k_fc_reduce<<<72 * BATCH / 256, 256, 0, stream>>>(P, fcb, (float*)d_out);
}

// Round 7
// 262.524 us; speedup vs baseline: 1.3602x; 1.3602x over previous
//
#include <hip/hip_runtime.h>
#include <hip/hip_bf16.h>

#define N_NODES 61440
#define NEDGE   491520
#define BATCH   2048
#define TT      30
#define C1      128
#define C2      512
#define C3      128
#define FCK     3840   // 128*30
#define MAXDEG  40     // Poisson(8) tail: P(deg>40) ~ 1e-11

typedef float floatx16 __attribute__((ext_vector_type(16)));
typedef __bf16 bfrag   __attribute__((ext_vector_type(8)));

static __device__ __forceinline__ unsigned short f2bf(float f) {
    unsigned u = __float_as_uint(f);
    u = u + 0x7fffu + ((u >> 16) & 1u);
    return (unsigned short)(u >> 16);
}
static __device__ __forceinline__ bfrag ldf(const void* p) { return *(const bfrag*)p; }
#define MFMA(a, b, c) __builtin_amdgcn_mfma_f32_32x32x16_bf16(a, b, c, 0, 0, 0)

// ---------------------------------------------------------------- GCN part

// Bucket src by dst; eidx transposed [slot][node] so gather reads coalesce.
__global__ void k_edges(const int* __restrict__ e32, int* __restrict__ cnt,
                        int* __restrict__ eidx) {
    int i = blockIdx.x * blockDim.x + threadIdx.x;
    if (i >= NEDGE) return;
    bool is64 = (e32[1] == 0) & (e32[3] == 0) & (e32[5] == 0) & (e32[7] == 0);
    int s, d;
    if (is64) { s = e32[2 * i]; d = e32[2 * (NEDGE + i)]; }
    else      { s = e32[i];     d = e32[NEDGE + i]; }
    int slot = atomicAdd(&cnt[d], 1);
    if (slot < MAXDEG) eidx[slot * N_NODES + d] = s;
}

__global__ void k_hdinv(const float* __restrict__ x, const float* __restrict__ gw,
                        const float* __restrict__ gb, const int* __restrict__ cnt,
                        float* __restrict__ dinv, float* __restrict__ hd,
                        float* __restrict__ g) {
    int i = blockIdx.x * blockDim.x + threadIdx.x;
    if (i >= N_NODES) return;
    float di = rsqrtf(1.0f + (float)cnt[i]);
    dinv[i] = di;
    float xi[12];
    const float4* xp = (const float4*)(x + i * 12);
    float4 a = xp[0], b4 = xp[1], c4 = xp[2];
    xi[0]=a.x; xi[1]=a.y; xi[2]=a.z; xi[3]=a.w;
    xi[4]=b4.x; xi[5]=b4.y; xi[6]=b4.z; xi[7]=b4.w;
    xi[8]=c4.x; xi[9]=c4.y; xi[10]=c4.z; xi[11]=c4.w;
    float d2 = di * di;
    #pragma unroll
    for (int c = 0; c < 12; c++) {
        float acc = 0.f;
        #pragma unroll
        for (int j = 0; j < 12; j++) acc += xi[j] * gw[c * 12 + j];
        hd[i * 12 + c] = di * acc;
        g[i * 12 + c] = d2 * acc + gb[c];
    }
}

// 3 threads per node, 4 channels each (720 blocks: better occupancy).
__global__ void k_gather(const int* __restrict__ cnt, const int* __restrict__ eidx,
                         const float* __restrict__ dinv, const float* __restrict__ hd,
                         float* __restrict__ g) {
    int part = blockIdx.x / 240;
    int d = (blockIdx.x - part * 240) * 256 + threadIdx.x;
    int n = cnt[d];
    if (n > MAXDEG) n = MAXDEG;
    float4 a = make_float4(0.f, 0.f, 0.f, 0.f);
    for (int j = 0; j < n; j++) {
        int s = eidx[j * N_NODES + d];           // coalesced across lanes
        float4 h = *(const float4*)(hd + (size_t)s * 12 + part * 4);
        a.x += h.x; a.y += h.y; a.z += h.z; a.w += h.w;
    }
    float di = dinv[d];
    float4* gp = (float4*)(g + (size_t)d * 12) + part;
    float4 gv = *gp;
    gv.x += di * a.x; gv.y += di * a.y; gv.z += di * a.z; gv.w += di * a.w;
    *gp = gv;
}

// ------------------------------------------------------- weight repacking
// Also zeroes cnt (runs before k_edges).
__global__ void k_repack(const float* __restrict__ cw0, const float* __restrict__ dw0,
                         const float* __restrict__ cw1, const float* __restrict__ dw1,
                         const float* __restrict__ cw2, const float* __restrict__ dw2,
                         const float* __restrict__ fcw,
                         float* __restrict__ w0T, float* __restrict__ d0T,
                         unsigned short* __restrict__ W1f, unsigned short* __restrict__ D1f,
                         unsigned short* __restrict__ W2f, unsigned short* __restrict__ D2f,
                         unsigned short* __restrict__ FCWf, int* __restrict__ cnt) {
    int i = blockIdx.x * blockDim.x + threadIdx.x;
    if (i < N_NODES) cnt[i] = 0;
    if (i < 36 * 128) { int oc = i & 127, r = i >> 7; w0T[i] = cw0[oc * 36 + r]; }
    if (i < 12 * 128) { int oc = i & 127, ic = i >> 7; d0T[i] = dw0[oc * 12 + ic]; }
    if (i < 196608) {                       // W1f
        int pos = i & 511, f = i >> 9;
        int lane = pos >> 3, e = pos & 7;
        int oct = f & 15, q = (f >> 4) & 7, tap = f >> 7;
        int oc = oct * 32 + (lane & 31), ic = q * 16 + (lane >> 5) * 8 + e;
        W1f[i] = f2bf(cw1[(oc * 128 + ic) * 3 + tap]);
    } else if (i < 262144) {                // D1f
        int j = i - 196608;
        int pos = j & 511, f = j >> 9;
        int lane = pos >> 3, e = pos & 7;
        int oct = f & 15, q = f >> 4;
        int oc = oct * 32 + (lane & 31), ic = q * 16 + (lane >> 5) * 8 + e;
        D1f[j] = f2bf(dw1[oc * 128 + ic]);
    } else if (i < 458752) {                // W2f
        int j = i - 262144;
        int pos = j & 511, f = j >> 9;
        int lane = pos >> 3, e = pos & 7;
        int oct = f & 3, q = (f >> 2) & 31, tap = f >> 7;
        int oc = oct * 32 + (lane & 31), ic = q * 16 + (lane >> 5) * 8 + e;
        W2f[j] = f2bf(cw2[(oc * 512 + ic) * 3 + tap]);
    } else if (i < 524288) {                // D2f
        int j = i - 458752;
        int pos = j & 511, f = j >> 9;
        int lane = pos >> 3, e = pos & 7;
        int oct = f & 3, q = f >> 2;
        int oc = oct * 32 + (lane & 31), ic = q * 16 + (lane >> 5) * 8 + e;
        D2f[j] = f2bf(dw2[oc * 512 + ic]);
    } else if (i < 892928) {                // FCWf (240*3 frags)
        int j = i - 524288;
        int pos = j & 511, f = j >> 9;
        int lane = pos >> 3, e = pos & 7;
        int oct = f % 3, q = f / 3;
        int o = oct * 32 + (lane & 31);
        int k = q * 16 + (lane >> 5) * 8 + e;
        float v = (o < 72) ? fcw[o * 3840 + (k & 127) * 30 + (k >> 7)] : 0.f;
        FCWf[j] = f2bf(v);
    }
}

// ------------------------------------------------------------ TCN block 0
// 12 -> 128, k=3 dil=1, + 1x1 down. 4 batch/WG. LDS-staged coalesced output.
__global__ __launch_bounds__(256) void k_block0(
        const float* __restrict__ g, const float* __restrict__ w0T,
        const float* __restrict__ d0T, const float* __restrict__ cb0,
        const float* __restrict__ db0, unsigned short* __restrict__ X1b) {
    __shared__ float wl[36 * 128];
    __shared__ float dl[12 * 128];
    __shared__ float cbl[128], dbl[128];
    __shared__ float x0[4 * TT * 12];
    __shared__ __align__(16) unsigned short st[2][TT * 136];
    int tid = threadIdx.x;
    int b0 = blockIdx.x * 4;
    for (int i = tid; i < 36 * 128; i += 256) wl[i] = w0T[i];
    for (int i = tid; i < 12 * 128; i += 256) dl[i] = d0T[i];
    if (tid < 128) { cbl[tid] = cb0[tid]; dbl[tid] = db0[tid]; }
    for (int i = tid; i < 4 * TT * 12; i += 256) x0[i] = g[b0 * TT * 12 + i];
    __syncthreads();
    int oc = tid & 127, half = tid >> 7;
    float cb = cbl[oc], db = dbl[oc];
    for (int bi = 0; bi < 2; bi++) {
        int bl = bi * 2 + half;
        const float* xb = x0 + bl * (TT * 12);
        float conv[TT], res[TT];
        #pragma unroll
        for (int t = 0; t < TT; t++) { conv[t] = 0.f; res[t] = 0.f; }
        #pragma unroll
        for (int ic = 0; ic < 12; ic++) {
            float w0v = wl[(ic * 3 + 0) * 128 + oc];
            float w1v = wl[(ic * 3 + 1) * 128 + oc];
            float w2v = wl[(ic * 3 + 2) * 128 + oc];
            float dv  = dl[ic * 128 + oc];
            #pragma unroll
            for (int t = 0; t < TT; t++) {
                float xv = xb[t * 12 + ic];
                conv[t] += w2v * xv;
                if (t + 1 < TT) conv[t + 1] += w1v * xv;
                if (t + 2 < TT) conv[t + 2] += w0v * xv;
                res[t] += dv * xv;
            }
        }
        #pragma unroll
        for (int t = 0; t < TT; t++) {
            float o1 = fmaxf(conv[t] + cb, 0.f);
            st[half][t * 136 + oc] = f2bf(fmaxf(o1 + res[t] + db, 0.f));
        }
        __syncthreads();
        for (int idx = tid; idx < 2 * TT * 16; idx += 256) {
            int h = idx / (TT * 16), rem = idx - h * (TT * 16);
            int row = rem >> 4, seg = rem & 15;
            *(uint4*)(X1b + (size_t)((b0 + bi * 2 + h) * TT + row) * 128 + seg * 8) =
                *(const uint4*)(&st[h][row * 136 + seg * 8]);
        }
        __syncthreads();
    }
}

// -------------------------------------------------- TCN blocks 1+2, MFMA
// 1 batch/WG, 256 threads, 40.7 KB LDS -> 3 WG/CU = 12 waves/CU (3/SIMD).
// Round-5 inner loops with the bl dimension removed (acc live-set -32 regs).
// No launch_bounds min-waves: the round-6 spill showed forcing regs is fatal.
__global__ __launch_bounds__(256) void k_tcn12(
        const unsigned short* __restrict__ X1b,
        const unsigned short* __restrict__ W1f, const unsigned short* __restrict__ D1f,
        const float* __restrict__ cb1, const float* __restrict__ db1,
        const unsigned short* __restrict__ W2f, const unsigned short* __restrict__ D2f,
        const float* __restrict__ cb2, const float* __restrict__ db2,
        unsigned short* __restrict__ X3b) {
    __shared__ __align__(16) unsigned short X1l[31 * 136];  // rows 0..29 data, 30 = zeros
    __shared__ __align__(16) unsigned short X2l[31 * 520];
    const int tid  = threadIdx.x;
    const int lane = tid & 63;
    const int wave = tid >> 6;
    const int tcol = lane & 31;
    const int half = lane >> 5;
    const int b = blockIdx.x;

    auto ldw1 = [&](bfrag* dst, int oct, int qc) {
        #pragma unroll
        for (int tap = 0; tap < 3; tap++)
            #pragma unroll
            for (int qq = 0; qq < 4; qq++)
                dst[tap * 4 + qq] =
                    ldf(W1f + (((tap * 8 + qc * 4 + qq) * 16 + oct) << 9) + lane * 8);
        #pragma unroll
        for (int qq = 0; qq < 4; qq++)
            dst[12 + qq] = ldf(D1f + (((qc * 4 + qq) * 16 + oct) << 9) + lane * 8);
    };
    auto ldw2 = [&](bfrag* dst, int oct, int qc) {
        #pragma unroll
        for (int tap = 0; tap < 3; tap++)
            #pragma unroll
            for (int qq = 0; qq < 4; qq++)
                dst[tap * 4 + qq] =
                    ldf(W2f + (((tap * 32 + qc * 4 + qq) * 4 + oct) << 9) + lane * 8);
        #pragma unroll
        for (int qq = 0; qq < 4; qq++)
            dst[12 + qq] = ldf(D2f + (((qc * 4 + qq) * 4 + oct) << 9) + lane * 8);
    };

    for (int idx = tid; idx < 480; idx += 256) {
        int row = idx >> 4, seg = idx & 15;
        *(uint4*)(X1l + row * 136 + seg * 8) =
            *(const uint4*)(X1b + ((size_t)(b * 30 + row) << 7) + seg * 8);
    }
    if (tid < 17) *(uint4*)(X1l + 30 * 136 + tid * 8) = make_uint4(0, 0, 0, 0);
    if (tid < 65) *(uint4*)(X2l + 30 * 520 + tid * 8) = make_uint4(0, 0, 0, 0);
    __syncthreads();

    // ---- phase 1: block1 (128->512, k=3 dil=3) + 1x1 down  -> X2l (bf16)
    {
        bfrag wf[2][16];
        ldw1(wf[0], wave, 0);
        floatx16 accc = 0, accd = 0;
        #pragma unroll
        for (int s = 0; s < 8; s++) {
            const int qc = s & 1;
            const int oct = (s >> 1) * 4 + wave;
            if (qc == 0) { accc = 0; accd = 0; }
            if (s < 7)
                ldw1(wf[(s + 1) & 1], ((s + 1) >> 1) * 4 + wave, (s + 1) & 1);
            bfrag bx[3][4];
            #pragma unroll
            for (int si = 0; si < 3; si++) {
                int trow = tcol - si * 3;
                const unsigned short* rp = ((unsigned)trow < 30u)
                    ? (X1l + trow * 136) : (X1l + 30 * 136);
                #pragma unroll
                for (int qq = 0; qq < 4; qq++)
                    bx[si][qq] = ldf(rp + (qc * 4 + qq) * 16 + half * 8);
            }
            #pragma unroll
            for (int qq = 0; qq < 4; qq++) {
                accc = MFMA(wf[s & 1][8 + qq],  bx[0][qq], accc);
                accc = MFMA(wf[s & 1][4 + qq],  bx[1][qq], accc);
                accc = MFMA(wf[s & 1][qq],      bx[2][qq], accc);
                accd = MFMA(wf[s & 1][12 + qq], bx[0][qq], accd);
            }
            if (qc == 1 && tcol < 30) {
                unsigned short* wp = X2l + tcol * 520 + oct * 32 + half * 4;
                #pragma unroll
                for (int gi = 0; gi < 4; gi++) {
                    int ocb = oct * 32 + half * 4 + gi * 8;
                    float4 cbv = *(const float4*)(cb1 + ocb);
                    float4 dbv = *(const float4*)(db1 + ocb);
                    float v0 = fmaxf(fmaxf(accc[gi*4+0] + cbv.x, 0.f) + accd[gi*4+0] + dbv.x, 0.f);
                    float v1 = fmaxf(fmaxf(accc[gi*4+1] + cbv.y, 0.f) + accd[gi*4+1] + dbv.y, 0.f);
                    float v2 = fmaxf(fmaxf(accc[gi*4+2] + cbv.z, 0.f) + accd[gi*4+2] + dbv.z, 0.f);
                    float v3 = fmaxf(fmaxf(accc[gi*4+3] + cbv.w, 0.f) + accd[gi*4+3] + dbv.w, 0.f);
                    unsigned p0 = (unsigned)f2bf(v0) | ((unsigned)f2bf(v1) << 16);
                    unsigned p1 = (unsigned)f2bf(v2) | ((unsigned)f2bf(v3) << 16);
                    *(uint2*)(wp + gi * 8) = make_uint2(p0, p1);
                }
            }
        }
    }
    __syncthreads();

    // ---- phase 2: block2 (512->128, k=3 dil=9) + 1x1 down -> staged X3
    {
        const int oct = wave;
        bfrag wf[2][16];
        ldw2(wf[0], oct, 0);
        floatx16 accc = 0, accd = 0;
        #pragma unroll
        for (int qc = 0; qc < 8; qc++) {
            if (qc < 7) ldw2(wf[(qc + 1) & 1], oct, qc + 1);
            bfrag bx[3][4];
            #pragma unroll
            for (int si = 0; si < 3; si++) {
                int trow = tcol - si * 9;
                const unsigned short* rp = ((unsigned)trow < 30u)
                    ? (X2l + trow * 520) : (X2l + 30 * 520);
                #pragma unroll
                for (int qq = 0; qq < 4; qq++)
                    bx[si][qq] = ldf(rp + (qc * 4 + qq) * 16 + half * 8);
            }
            #pragma unroll
            for (int qq = 0; qq < 4; qq++) {
                accc = MFMA(wf[qc & 1][8 + qq],  bx[0][qq], accc);
                accc = MFMA(wf[qc & 1][4 + qq],  bx[1][qq], accc);
                accc = MFMA(wf[qc & 1][qq],      bx[2][qq], accc);
                accd = MFMA(wf[qc & 1][12 + qq], bx[0][qq], accd);
            }
        }
        if (tcol < 30) {   // stage into X1l area (free after phase 1)
            unsigned short* wp = X1l + tcol * 136 + oct * 32 + half * 4;
            #pragma unroll
            for (int gi = 0; gi < 4; gi++) {
                int ocb = oct * 32 + half * 4 + gi * 8;
                float4 cbv = *(const float4*)(cb2 + ocb);
                float4 dbv = *(const float4*)(db2 + ocb);
                float v0 = fmaxf(fmaxf(accc[gi*4+0] + cbv.x, 0.f) + accd[gi*4+0] + dbv.x, 0.f);
                float v1 = fmaxf(fmaxf(accc[gi*4+1] + cbv.y, 0.f) + accd[gi*4+1] + dbv.y, 0.f);
                float v2 = fmaxf(fmaxf(accc[gi*4+2] + cbv.z, 0.f) + accd[gi*4+2] + dbv.z, 0.f);
                float v3 = fmaxf(fmaxf(accc[gi*4+3] + cbv.w, 0.f) + accd[gi*4+3] + dbv.w, 0.f);
                unsigned p0 = (unsigned)f2bf(v0) | ((unsigned)f2bf(v1) << 16);
                unsigned p1 = (unsigned)f2bf(v2) | ((unsigned)f2bf(v3) << 16);
                *(uint2*)(wp + gi * 8) = make_uint2(p0, p1);
            }
        }
    }
    __syncthreads();
    // coalesced flush: 30 rows x 256 B contiguous
    for (int idx = tid; idx < 480; idx += 256) {
        int row = idx >> 4, seg = idx & 15;
        *(uint4*)(X3b + ((size_t)(b * 30 + row) << 7) + seg * 8) =
            *(const uint4*)(X1l + row * 136 + seg * 8);
    }
}

// ------------------------------------------------------------- FC (MFMA)
// B-operand staged through LDS (fixes 7.7 KB-strided per-lane gathers).
// P layout [kc][o(96)][b(2048)] for coalesced stores/reads.
__global__ __launch_bounds__(256) void k_fc_mfma(
        const unsigned short* __restrict__ X3b,
        const unsigned short* __restrict__ FCWf,
        float* __restrict__ P) {
    __shared__ __align__(16) unsigned short xt[128 * 248];   // 240 used + 8 pad
    const int tid  = threadIdx.x;
    const int lane = tid & 63;
    const int wave = tid >> 6;
    const int half = lane >> 5;
    const int bg = blockIdx.x & 15;
    const int kc = blockIdx.x >> 4;

    for (int idx = tid; idx < 128 * 32; idx += 256) {
        int row = idx >> 5, seg = idx & 31;
        if (seg < 30)
            *(uint4*)(xt + row * 248 + seg * 8) =
                *(const uint4*)(X3b + (size_t)(bg * 128 + row) * FCK + kc * 240 + seg * 8);
    }
    __syncthreads();

    const int bl = wave * 32 + (lane & 31);
    floatx16 acc[3];
    acc[0] = 0; acc[1] = 0; acc[2] = 0;
    #pragma unroll
    for (int ql = 0; ql < 15; ql++) {
        int q = kc * 15 + ql;
        bfrag bx = ldf(xt + bl * 248 + ql * 16 + half * 8);
        #pragma unroll
        for (int oct = 0; oct < 3; oct++) {
            bfrag af = ldf(FCWf + ((q * 3 + oct) << 9) + lane * 8);
            acc[oct] = MFMA(af, bx, acc[oct]);
        }
    }
    float* base = P + (size_t)kc * 96 * BATCH;
    const int b = bg * 128 + bl;
    #pragma unroll
    for (int oct = 0; oct < 3; oct++)
        #pragma unroll
        for (int j = 0; j < 16; j++) {
            int o = oct * 32 + half * 4 + (j >> 2) * 8 + (j & 3);
            base[(size_t)o * BATCH + b] = acc[oct][j];
        }
}

__global__ __launch_bounds__(256) void k_fc_reduce(
        const float* __restrict__ P, const float* __restrict__ fcb,
        float* __restrict__ out) {
    int j = blockIdx.x * blockDim.x + threadIdx.x;   // j = o*2048 + b, o<72
    int o = j >> 11, b = j & 2047;
    float acc = fcb[o];
    #pragma unroll
    for (int kc = 0; kc < 16; kc++)
        acc += P[((size_t)kc * 96 + o) * BATCH + b];
    out[b * 72 + o] = acc;
}

// ---------------------------------------------------------------- launch

extern "C" void kernel_launch(void* const* d_in, const int* in_sizes, int n_in,
                              void* d_out, int out_size, void* d_ws, size_t ws_size,
                              hipStream_t stream) {
    const float* x   = (const float*)d_in[0];
    const int*   e32 = (const int*)  d_in[1];
    const float* gw  = (const float*)d_in[2];
    const float* gb  = (const float*)d_in[3];
    const float* cw0 = (const float*)d_in[4];
    const float* cb0 = (const float*)d_in[5];
    const float* dw0 = (const float*)d_in[6];
    const float* db0 = (const float*)d_in[7];
    const float* cw1 = (const float*)d_in[8];
    const float* cb1 = (const float*)d_in[9];
    const float* dw1 = (const float*)d_in[10];
    const float* db1 = (const float*)d_in[11];
    const float* cw2 = (const float*)d_in[12];
    const float* cb2 = (const float*)d_in[13];
    const float* dw2 = (const float*)d_in[14];
    const float* db2 = (const float*)d_in[15];
    const float* fcw = (const float*)d_in[16];
    const float* fcb = (const float*)d_in[17];

    char* w = (char*)d_ws;
    auto alloc = [&](size_t bytes) {
        char* p = w;
        w += (bytes + 255) & ~(size_t)255;
        return p;
    };
    int*   cnt  = (int*)  alloc(N_NODES * 4);
    int*   eidx = (int*)  alloc((size_t)N_NODES * MAXDEG * 4);
    float* dinv = (float*)alloc(N_NODES * 4);
    float* hd   = (float*)alloc((size_t)N_NODES * 12 * 4);
    float* g    = (float*)alloc((size_t)N_NODES * 12 * 4);
    float* w0T  = (float*)alloc(36 * 128 * 4);
    float* d0T  = (float*)alloc(12 * 128 * 4);
    unsigned short* W1f  = (unsigned short*)alloc(196608 * 2);
    unsigned short* D1f  = (unsigned short*)alloc(65536 * 2);
    unsigned short* W2f  = (unsigned short*)alloc(196608 * 2);
    unsigned short* D2f  = (unsigned short*)alloc(65536 * 2);
    unsigned short* FCWf = (unsigned short*)alloc(368640 * 2);
    unsigned short* X1b  = (unsigned short*)alloc((size_t)BATCH * TT * C1 * 2);
    unsigned short* X3b  = (unsigned short*)alloc((size_t)BATCH * TT * C3 * 2);
    float* P    = (float*)alloc((size_t)16 * 96 * BATCH * 4);

    k_repack<<<(892928 + 255) / 256, 256, 0, stream>>>(
        cw0, dw0, cw1, dw1, cw2, dw2, fcw, w0T, d0T, W1f, D1f, W2f, D2f, FCWf, cnt);
    k_edges<<<NEDGE / 256, 256, 0, stream>>>(e32, cnt, eidx);
    k_hdinv<<<N_NODES / 256, 256, 0, stream>>>(x, gw, gb, cnt, dinv, hd, g);
    k_gather<<<720, 256, 0, stream>>>(cnt, eidx, dinv, hd, g);
    k_block0<<<BATCH / 4, 256, 0, stream>>>(g, w0T, d0T, cb0, db0, X1b);
    k_tcn12<<<BATCH, 256, 0, stream>>>(X1b, W1f, D1f, cb1, db1,
                                       W2f, D2f, cb2, db2, X3b);
    k_fc_mfma<<<256, 256, 0, stream>>>(X3b, FCWf, P);
    k_fc_reduce<<<72 * BATCH / 256, 256, 0, stream>>>(P, fcb, (float*)d_out);
}

// Round 8
// 258.900 us; speedup vs baseline: 1.3793x; 1.0140x over previous
//
#include <hip/hip_runtime.h>
#include <hip/hip_bf16.h>

#define N_NODES 61440
#define NEDGE   491520
#define BATCH   2048
#define TT      30
#define C1      128
#define C2      512
#define C3      128
#define FCK     3840   // 128*30
#define MAXDEG  40     // Poisson(8) tail: P(deg>40) ~ 1e-11

typedef float floatx16 __attribute__((ext_vector_type(16)));
typedef __bf16 bfrag   __attribute__((ext_vector_type(8)));

static __device__ __forceinline__ unsigned short f2bf(float f) {
    unsigned u = __float_as_uint(f);
    u = u + 0x7fffu + ((u >> 16) & 1u);
    return (unsigned short)(u >> 16);
}
static __device__ __forceinline__ bfrag ldf(const void* p) { return *(const bfrag*)p; }
#define MFMA(a, b, c) __builtin_amdgcn_mfma_f32_32x32x16_bf16(a, b, c, 0, 0, 0)

// ---------------------------------------------------------------- GCN part

// Bucket src by dst; eidx transposed [slot][node] so gather reads coalesce.
__global__ void k_edges(const int* __restrict__ e32, int* __restrict__ cnt,
                        int* __restrict__ eidx) {
    int i = blockIdx.x * blockDim.x + threadIdx.x;
    if (i >= NEDGE) return;
    bool is64 = (e32[1] == 0) & (e32[3] == 0) & (e32[5] == 0) & (e32[7] == 0);
    int s, d;
    if (is64) { s = e32[2 * i]; d = e32[2 * (NEDGE + i)]; }
    else      { s = e32[i];     d = e32[NEDGE + i]; }
    int slot = atomicAdd(&cnt[d], 1);
    if (slot < MAXDEG) eidx[slot * N_NODES + d] = s;
}

__global__ void k_hdinv(const float* __restrict__ x, const float* __restrict__ gw,
                        const float* __restrict__ gb, const int* __restrict__ cnt,
                        float* __restrict__ dinv, float* __restrict__ hd,
                        float* __restrict__ g) {
    int i = blockIdx.x * blockDim.x + threadIdx.x;
    if (i >= N_NODES) return;
    float di = rsqrtf(1.0f + (float)cnt[i]);
    dinv[i] = di;
    float xi[12];
    const float4* xp = (const float4*)(x + i * 12);
    float4 a = xp[0], b4 = xp[1], c4 = xp[2];
    xi[0]=a.x; xi[1]=a.y; xi[2]=a.z; xi[3]=a.w;
    xi[4]=b4.x; xi[5]=b4.y; xi[6]=b4.z; xi[7]=b4.w;
    xi[8]=c4.x; xi[9]=c4.y; xi[10]=c4.z; xi[11]=c4.w;
    float d2 = di * di;
    #pragma unroll
    for (int c = 0; c < 12; c++) {
        float acc = 0.f;
        #pragma unroll
        for (int j = 0; j < 12; j++) acc += xi[j] * gw[c * 12 + j];
        hd[i * 12 + c] = di * acc;
        g[i * 12 + c] = d2 * acc + gb[c];
    }
}

// 3 threads per node, 4 channels each.
__global__ void k_gather(const int* __restrict__ cnt, const int* __restrict__ eidx,
                         const float* __restrict__ dinv, const float* __restrict__ hd,
                         float* __restrict__ g) {
    int part = blockIdx.x / 240;
    int d = (blockIdx.x - part * 240) * 256 + threadIdx.x;
    int n = cnt[d];
    if (n > MAXDEG) n = MAXDEG;
    float4 a = make_float4(0.f, 0.f, 0.f, 0.f);
    for (int j = 0; j < n; j++) {
        int s = eidx[j * N_NODES + d];           // coalesced across lanes
        float4 h = *(const float4*)(hd + (size_t)s * 12 + part * 4);
        a.x += h.x; a.y += h.y; a.z += h.z; a.w += h.w;
    }
    float di = dinv[d];
    float4* gp = (float4*)(g + (size_t)d * 12) + part;
    float4 gv = *gp;
    gv.x += di * a.x; gv.y += di * a.y; gv.z += di * a.z; gv.w += di * a.w;
    *gp = gv;
}

// ------------------------------------------------------- weight repacking
// Frag-linear bf16 for MFMA A-operand, 32x32x16:
//   m/oc = oct*32 + (lane&31); k = q*16 + (lane>>5)*8 + e.
// W0f: frag = q*4 + oct (q<3: im2col K=48 of 64, k=tap*12+ic); D0f: frag = oct (K=16, k=ic)
// W1f: frag = (tap*8 + q)*16 + oct ; D1f: frag = q*16 + oct
// W2f: frag = (tap*32 + q)*4 + oct ; D2f: frag = q*4 + oct
// FCWf: frag = q*3 + oct. Also zeroes cnt.
__global__ void k_repack(const float* __restrict__ cw0, const float* __restrict__ dw0,
                         const float* __restrict__ cw1, const float* __restrict__ dw1,
                         const float* __restrict__ cw2, const float* __restrict__ dw2,
                         const float* __restrict__ fcw,
                         unsigned short* __restrict__ W0f, unsigned short* __restrict__ D0f,
                         unsigned short* __restrict__ W1f, unsigned short* __restrict__ D1f,
                         unsigned short* __restrict__ W2f, unsigned short* __restrict__ D2f,
                         unsigned short* __restrict__ FCWf, int* __restrict__ cnt) {
    int i = blockIdx.x * blockDim.x + threadIdx.x;
    if (i < N_NODES) cnt[i] = 0;
    if (i < 6144) {                         // W0f (12 frags)
        int pos = i & 511, f = i >> 9;
        int lane = pos >> 3, e = pos & 7;
        int oct = f & 3, q = f >> 2;
        int oc = oct * 32 + (lane & 31);
        int k = q * 16 + (lane >> 5) * 8 + e;
        float v = 0.f;
        if (k < 36) { int tap = k / 12, ic = k - tap * 12; v = cw0[oc * 36 + ic * 3 + tap]; }
        W0f[i] = f2bf(v);
    }
    if (i >= 6144 && i < 8192) {            // D0f (4 frags)
        int j = i - 6144;
        int pos = j & 511, f = j >> 9;
        int lane = pos >> 3, e = pos & 7;
        int oc = f * 32 + (lane & 31);
        int k = (lane >> 5) * 8 + e;
        float v = (k < 12) ? dw0[oc * 12 + k] : 0.f;
        D0f[j] = f2bf(v);
    }
    if (i < 196608) {                       // W1f
        int pos = i & 511, f = i >> 9;
        int lane = pos >> 3, e = pos & 7;
        int oct = f & 15, q = (f >> 4) & 7, tap = f >> 7;
        int oc = oct * 32 + (lane & 31), ic = q * 16 + (lane >> 5) * 8 + e;
        W1f[i] = f2bf(cw1[(oc * 128 + ic) * 3 + tap]);
    } else if (i < 262144) {                // D1f
        int j = i - 196608;
        int pos = j & 511, f = j >> 9;
        int lane = pos >> 3, e = pos & 7;
        int oct = f & 15, q = f >> 4;
        int oc = oct * 32 + (lane & 31), ic = q * 16 + (lane >> 5) * 8 + e;
        D1f[j] = f2bf(dw1[oc * 128 + ic]);
    } else if (i < 458752) {                // W2f
        int j = i - 262144;
        int pos = j & 511, f = j >> 9;
        int lane = pos >> 3, e = pos & 7;
        int oct = f & 3, q = (f >> 2) & 31, tap = f >> 7;
        int oc = oct * 32 + (lane & 31), ic = q * 16 + (lane >> 5) * 8 + e;
        W2f[j] = f2bf(cw2[(oc * 512 + ic) * 3 + tap]);
    } else if (i < 524288) {                // D2f
        int j = i - 458752;
        int pos = j & 511, f = j >> 9;
        int lane = pos >> 3, e = pos & 7;
        int oct = f & 3, q = f >> 2;
        int oc = oct * 32 + (lane & 31), ic = q * 16 + (lane >> 5) * 8 + e;
        D2f[j] = f2bf(dw2[oc * 512 + ic]);
    } else if (i < 892928) {                // FCWf (240*3 frags)
        int j = i - 524288;
        int pos = j & 511, f = j >> 9;
        int lane = pos >> 3, e = pos & 7;
        int oct = f % 3, q = f / 3;
        int o = oct * 32 + (lane & 31);
        int k = q * 16 + (lane >> 5) * 8 + e;
        float v = (o < 72) ? fcw[o * 3840 + (k & 127) * 30 + (k >> 7)] : 0.f;
        FCWf[j] = f2bf(v);
    }
}

// ---------------------------------------- TCN blocks 0+1+2 fused, MFMA
// 512 threads (8 waves), 2 batch/WG, 80.4 KB LDS -> 2 WG/CU = 16 waves/CU.
// JIT weight loads (round 7 showed compiler ignores explicit dbuf; 104 regs).
// Phase 0: block0 (12->128, im2col K=64) from g, result straight into X1l.
// Phase 1: block1 (128->512, dil=3) -> X2l. Phase 2: block2 (512->128,
// dil=9) -> staged in X1l -> coalesced flush to X3b.
__global__ __launch_bounds__(512) void k_tcn12(
        const float* __restrict__ g,
        const unsigned short* __restrict__ W0f, const unsigned short* __restrict__ D0f,
        const float* __restrict__ cb0, const float* __restrict__ db0,
        const unsigned short* __restrict__ W1f, const unsigned short* __restrict__ D1f,
        const float* __restrict__ cb1, const float* __restrict__ db1,
        const unsigned short* __restrict__ W2f, const unsigned short* __restrict__ D2f,
        const float* __restrict__ cb2, const float* __restrict__ db2,
        unsigned short* __restrict__ X3b) {
    __shared__ __align__(16) unsigned short X1l[61 * 136];  // rows 0..59 data, 60 = zeros
    __shared__ __align__(16) unsigned short X2l[61 * 520];
    const int tid  = threadIdx.x;
    const int lane = tid & 63;
    const int wave = tid >> 6;      // 0..7
    const int tcol = lane & 31;
    const int half = lane >> 5;
    const int b0 = blockIdx.x * 2;

    // ---- stage A: im2col for block0 into Bl (overlaid on X2l) + zero rows
    unsigned short* Bl = X2l;       // 2 x 32 rows x 72 shorts = 9.2 KB
    for (int idx = tid; idx < 4096; idx += 512) {
        int bl = idx >> 11, rem = idx & 2047;
        int t = rem >> 6, k = rem & 63;
        float v = 0.f;
        if (t < 30) {
            if (k < 36) {
                int tap = k / 12, ic = k - tap * 12;
                int tt = t + tap - 2;
                if (tt >= 0) v = g[((size_t)(b0 + bl) * 30 + tt) * 12 + ic];
            } else if (k >= 48 && k < 60) {
                v = g[((size_t)(b0 + bl) * 30 + t) * 12 + (k - 48)];
            }
        }
        Bl[bl * 2304 + t * 72 + k] = f2bf(v);
    }
    if (tid < 17) *(uint4*)(X1l + 60 * 136 + tid * 8) = make_uint4(0, 0, 0, 0);
    __syncthreads();

    // ---- phase 0: block0 (12->128 + 1x1 down) -> X1l rows (bf16)
    {
        const int oct = wave >> 1;
        const int bl = wave & 1;
        bfrag aw0[3], ad0;
        #pragma unroll
        for (int q = 0; q < 3; q++)
            aw0[q] = ldf(W0f + ((q * 4 + oct) << 9) + lane * 8);
        ad0 = ldf(D0f + (oct << 9) + lane * 8);
        const unsigned short* rp = Bl + bl * 2304 + tcol * 72;
        bfrag bx0 = ldf(rp + half * 8);
        bfrag bx1 = ldf(rp + 16 + half * 8);
        bfrag bx2 = ldf(rp + 32 + half * 8);
        bfrag bxd = ldf(rp + 48 + half * 8);
        floatx16 accc = 0, accd = 0;
        accc = MFMA(aw0[0], bx0, accc);
        accc = MFMA(aw0[1], bx1, accc);
        accc = MFMA(aw0[2], bx2, accc);
        accd = MFMA(ad0, bxd, accd);
        if (tcol < 30) {
            unsigned short* wp = X1l + (bl * 30 + tcol) * 136 + oct * 32 + half * 4;
            #pragma unroll
            for (int gi = 0; gi < 4; gi++) {
                int ocb = oct * 32 + half * 4 + gi * 8;
                float4 cbv = *(const float4*)(cb0 + ocb);
                float4 dbv = *(const float4*)(db0 + ocb);
                float v0 = fmaxf(fmaxf(accc[gi*4+0] + cbv.x, 0.f) + accd[gi*4+0] + dbv.x, 0.f);
                float v1 = fmaxf(fmaxf(accc[gi*4+1] + cbv.y, 0.f) + accd[gi*4+1] + dbv.y, 0.f);
                float v2 = fmaxf(fmaxf(accc[gi*4+2] + cbv.z, 0.f) + accd[gi*4+2] + dbv.z, 0.f);
                float v3 = fmaxf(fmaxf(accc[gi*4+3] + cbv.w, 0.f) + accd[gi*4+3] + dbv.w, 0.f);
                unsigned p0 = (unsigned)f2bf(v0) | ((unsigned)f2bf(v1) << 16);
                unsigned p1 = (unsigned)f2bf(v2) | ((unsigned)f2bf(v3) << 16);
                *(uint2*)(wp + gi * 8) = make_uint2(p0, p1);
            }
        }
    }
    // zero row of X2l (outside Bl region; write before barrier)
    if (tid >= 64 && tid < 129)
        *(uint4*)(X2l + 60 * 520 + (tid - 64) * 8) = make_uint4(0, 0, 0, 0);
    __syncthreads();

    // ---- phase 1: block1 (128->512, k=3 dil=3) + 1x1 down  -> X2l (bf16)
    // 32 units (16 oct x 2 bl) over 8 waves.
    for (int i = 0; i < 4; i++) {
        int u = i * 8 + wave;
        int oct = u & 15;
        int bl = u >> 4;
        floatx16 accc = 0, accd = 0;
        #pragma unroll
        for (int qc = 0; qc < 2; qc++) {
            bfrag aw[12], ad[4];
            #pragma unroll
            for (int tap = 0; tap < 3; tap++)
                #pragma unroll
                for (int qq = 0; qq < 4; qq++)
                    aw[tap * 4 + qq] =
                        ldf(W1f + (((tap * 8 + qc * 4 + qq) * 16 + oct) << 9) + lane * 8);
            #pragma unroll
            for (int qq = 0; qq < 4; qq++)
                ad[qq] = ldf(D1f + (((qc * 4 + qq) * 16 + oct) << 9) + lane * 8);
            bfrag bx[3][4];
            #pragma unroll
            for (int si = 0; si < 3; si++) {
                int trow = tcol - si * 3;
                const unsigned short* rp = ((unsigned)trow < 30u)
                    ? (X1l + (bl * 30 + trow) * 136) : (X1l + 60 * 136);
                #pragma unroll
                for (int qq = 0; qq < 4; qq++)
                    bx[si][qq] = ldf(rp + (qc * 4 + qq) * 16 + half * 8);
            }
            #pragma unroll
            for (int qq = 0; qq < 4; qq++) {
                accc = MFMA(aw[8 + qq], bx[0][qq], accc);
                accc = MFMA(aw[4 + qq], bx[1][qq], accc);
                accc = MFMA(aw[qq],     bx[2][qq], accc);
                accd = MFMA(ad[qq],     bx[0][qq], accd);
            }
        }
        if (tcol < 30) {
            unsigned short* wp = X2l + (bl * 30 + tcol) * 520 + oct * 32 + half * 4;
            #pragma unroll
            for (int gi = 0; gi < 4; gi++) {
                int ocb = oct * 32 + half * 4 + gi * 8;
                float4 cbv = *(const float4*)(cb1 + ocb);
                float4 dbv = *(const float4*)(db1 + ocb);
                float v0 = fmaxf(fmaxf(accc[gi*4+0] + cbv.x, 0.f) + accd[gi*4+0] + dbv.x, 0.f);
                float v1 = fmaxf(fmaxf(accc[gi*4+1] + cbv.y, 0.f) + accd[gi*4+1] + dbv.y, 0.f);
                float v2 = fmaxf(fmaxf(accc[gi*4+2] + cbv.z, 0.f) + accd[gi*4+2] + dbv.z, 0.f);
                float v3 = fmaxf(fmaxf(accc[gi*4+3] + cbv.w, 0.f) + accd[gi*4+3] + dbv.w, 0.f);
                unsigned p0 = (unsigned)f2bf(v0) | ((unsigned)f2bf(v1) << 16);
                unsigned p1 = (unsigned)f2bf(v2) | ((unsigned)f2bf(v3) << 16);
                *(uint2*)(wp + gi * 8) = make_uint2(p0, p1);
            }
        }
    }
    __syncthreads();

    // ---- phase 2: block2 (512->128, k=3 dil=9) + 1x1 down -> staged X3
    // 8 units (4 oct x 2 bl) over 8 waves.
    {
        const int oct = wave >> 1;
        const int bl = wave & 1;
        floatx16 accc = 0, accd = 0;
        #pragma unroll
        for (int qc = 0; qc < 8; qc++) {
            bfrag aw[12], ad[4];
            #pragma unroll
            for (int tap = 0; tap < 3; tap++)
                #pragma unroll
                for (int qq = 0; qq < 4; qq++)
                    aw[tap * 4 + qq] =
                        ldf(W2f + (((tap * 32 + qc * 4 + qq) * 4 + oct) << 9) + lane * 8);
            #pragma unroll
            for (int qq = 0; qq < 4; qq++)
                ad[qq] = ldf(D2f + (((qc * 4 + qq) * 4 + oct) << 9) + lane * 8);
            bfrag bx[3][4];
            #pragma unroll
            for (int si = 0; si < 3; si++) {
                int trow = tcol - si * 9;
                const unsigned short* rp = ((unsigned)trow < 30u)
                    ? (X2l + (bl * 30 + trow) * 520) : (X2l + 60 * 520);
                #pragma unroll
                for (int qq = 0; qq < 4; qq++)
                    bx[si][qq] = ldf(rp + (qc * 4 + qq) * 16 + half * 8);
            }
            #pragma unroll
            for (int qq = 0; qq < 4; qq++) {
                accc = MFMA(aw[8 + qq], bx[0][qq], accc);
                accc = MFMA(aw[4 + qq], bx[1][qq], accc);
                accc = MFMA(aw[qq],     bx[2][qq], accc);
                accd = MFMA(ad[qq],     bx[0][qq], accd);
            }
        }
        if (tcol < 30) {   // stage into X1l area (free after phase 1)
            unsigned short* wp = X1l + (bl * 30 + tcol) * 136 + oct * 32 + half * 4;
            #pragma unroll
            for (int gi = 0; gi < 4; gi++) {
                int ocb = oct * 32 + half * 4 + gi * 8;
                float4 cbv = *(const float4*)(cb2 + ocb);
                float4 dbv = *(const float4*)(db2 + ocb);
                float v0 = fmaxf(fmaxf(accc[gi*4+0] + cbv.x, 0.f) + accd[gi*4+0] + dbv.x, 0.f);
                float v1 = fmaxf(fmaxf(accc[gi*4+1] + cbv.y, 0.f) + accd[gi*4+1] + dbv.y, 0.f);
                float v2 = fmaxf(fmaxf(accc[gi*4+2] + cbv.z, 0.f) + accd[gi*4+2] + dbv.z, 0.f);
                float v3 = fmaxf(fmaxf(accc[gi*4+3] + cbv.w, 0.f) + accd[gi*4+3] + dbv.w, 0.f);
                unsigned p0 = (unsigned)f2bf(v0) | ((unsigned)f2bf(v1) << 16);
                unsigned p1 = (unsigned)f2bf(v2) | ((unsigned)f2bf(v3) << 16);
                *(uint2*)(wp + gi * 8) = make_uint2(p0, p1);
            }
        }
    }
    __syncthreads();
    // coalesced flush: 60 rows x 256 B contiguous
    for (int idx = tid; idx < 960; idx += 512) {
        int row = idx >> 4, seg = idx & 15;
        *(uint4*)(X3b + ((size_t)(b0 * 30 + row) << 7) + seg * 8) =
            *(const uint4*)(X1l + row * 136 + seg * 8);
    }
}

// ------------------------------------------------------------- FC (MFMA)
// B-operand staged through LDS. P layout [kc][o(96)][b(2048)].
__global__ __launch_bounds__(256) void k_fc_mfma(
        const unsigned short* __restrict__ X3b,
        const unsigned short* __restrict__ FCWf,
        float* __restrict__ P) {
    __shared__ __align__(16) unsigned short xt[128 * 248];   // 240 used + 8 pad
    const int tid  = threadIdx.x;
    const int lane = tid & 63;
    const int wave = tid >> 6;
    const int half = lane >> 5;
    const int bg = blockIdx.x & 15;
    const int kc = blockIdx.x >> 4;

    for (int idx = tid; idx < 128 * 32; idx += 256) {
        int row = idx >> 5, seg = idx & 31;
        if (seg < 30)
            *(uint4*)(xt + row * 248 + seg * 8) =
                *(const uint4*)(X3b + (size_t)(bg * 128 + row) * FCK + kc * 240 + seg * 8);
    }
    __syncthreads();

    const int bl = wave * 32 + (lane & 31);
    floatx16 acc[3];
    acc[0] = 0; acc[1] = 0; acc[2] = 0;
    #pragma unroll
    for (int ql = 0; ql < 15; ql++) {
        int q = kc * 15 + ql;
        bfrag bx = ldf(xt + bl * 248 + ql * 16 + half * 8);
        #pragma unroll
        for (int oct = 0; oct < 3; oct++) {
            bfrag af = ldf(FCWf + ((q * 3 + oct) << 9) + lane * 8);
            acc[oct] = MFMA(af, bx, acc[oct]);
        }
    }
    float* base = P + (size_t)kc * 96 * BATCH;
    const int b = bg * 128 + bl;
    #pragma unroll
    for (int oct = 0; oct < 3; oct++)
        #pragma unroll
        for (int j = 0; j < 16; j++) {
            int o = oct * 32 + half * 4 + (j >> 2) * 8 + (j & 3);
            base[(size_t)o * BATCH + b] = acc[oct][j];
        }
}

__global__ __launch_bounds__(256) void k_fc_reduce(
        const float* __restrict__ P, const float* __restrict__ fcb,
        float* __restrict__ out) {
    int j = blockIdx.x * blockDim.x + threadIdx.x;   // j = o*2048 + b, o<72
    int o = j >> 11, b = j & 2047;
    float acc = fcb[o];
    #pragma unroll
    for (int kc = 0; kc < 16; kc++)
        acc += P[((size_t)kc * 96 + o) * BATCH + b];
    out[b * 72 + o] = acc;
}

// ---------------------------------------------------------------- launch

extern "C" void kernel_launch(void* const* d_in, const int* in_sizes, int n_in,
                              void* d_out, int out_size, void* d_ws, size_t ws_size,
                              hipStream_t stream) {
    const float* x   = (const float*)d_in[0];
    const int*   e32 = (const int*)  d_in[1];
    const float* gw  = (const float*)d_in[2];
    const float* gb  = (const float*)d_in[3];
    const float* cw0 = (const float*)d_in[4];
    const float* cb0 = (const float*)d_in[5];
    const float* dw0 = (const float*)d_in[6];
    const float* db0 = (const float*)d_in[7];
    const float* cw1 = (const float*)d_in[8];
    const float* cb1 = (const float*)d_in[9];
    const float* dw1 = (const float*)d_in[10];
    const float* db1 = (const float*)d_in[11];
    const float* cw2 = (const float*)d_in[12];
    const float* cb2 = (const float*)d_in[13];
    const float* dw2 = (const float*)d_in[14];
    const float* db2 = (const float*)d_in[15];
    const float* fcw = (const float*)d_in[16];
    const float* fcb = (const float*)d_in[17];

    char* w = (char*)d_ws;
    auto alloc = [&](size_t bytes) {
        char* p = w;
        w += (bytes + 255) & ~(size_t)255;
        return p;
    };
    int*   cnt  = (int*)  alloc(N_NODES * 4);
    int*   eidx = (int*)  alloc((size_t)N_NODES * MAXDEG * 4);
    float* dinv = (float*)alloc(N_NODES * 4);
    float* hd   = (float*)alloc((size_t)N_NODES * 12 * 4);
    float* g    = (float*)alloc((size_t)N_NODES * 12 * 4);
    unsigned short* W0f  = (unsigned short*)alloc(6144 * 2);
    unsigned short* D0f  = (unsigned short*)alloc(2048 * 2);
    unsigned short* W1f  = (unsigned short*)alloc(196608 * 2);
    unsigned short* D1f  = (unsigned short*)alloc(65536 * 2);
    unsigned short* W2f  = (unsigned short*)alloc(196608 * 2);
    unsigned short* D2f  = (unsigned short*)alloc(65536 * 2);
    unsigned short* FCWf = (unsigned short*)alloc(368640 * 2);
    unsigned short* X3b  = (unsigned short*)alloc((size_t)BATCH * TT * C3 * 2);
    float* P    = (float*)alloc((size_t)16 * 96 * BATCH * 4);

    k_repack<<<(892928 + 255) / 256, 256, 0, stream>>>(
        cw0, dw0, cw1, dw1, cw2, dw2, fcw, W0f, D0f, W1f, D1f, W2f, D2f, FCWf, cnt);
    k_edges<<<NEDGE / 256, 256, 0, stream>>>(e32, cnt, eidx);
    k_hdinv<<<N_NODES / 256, 256, 0, stream>>>(x, gw, gb, cnt, dinv, hd, g);
    k_gather<<<720, 256, 0, stream>>>(cnt, eidx, dinv, hd, g);
    k_tcn12<<<BATCH / 2, 512, 0, stream>>>(g, W0f, D0f, cb0, db0,
                                           W1f, D1f, cb1, db1,
                                           W2f, D2f, cb2, db2, X3b);
    k_fc_mfma<<<256, 256, 0, stream>>>(X3b, FCWf, P);
    k_fc_reduce<<<72 * BATCH / 256, 256, 0, stream>>>(P, fcb, (float*)d_out);
}

// Round 9
// 245.421 us; speedup vs baseline: 1.4550x; 1.0549x over previous
//
#include <hip/hip_runtime.h>
#include <hip/hip_bf16.h>

#define N_NODES 61440
#define NEDGE   491520
#define BATCH   2048
#define TT      30
#define C1      128
#define C2      512
#define C3      128
#define FCK     3840   // 128*30
#define MAXDEG  40     // Poisson(8) tail: P(deg>40) ~ 1e-11

typedef float floatx16 __attribute__((ext_vector_type(16)));
typedef __bf16 bfrag   __attribute__((ext_vector_type(8)));

static __device__ __forceinline__ unsigned short f2bf(float f) {
    unsigned u = __float_as_uint(f);
    u = u + 0x7fffu + ((u >> 16) & 1u);
    return (unsigned short)(u >> 16);
}
static __device__ __forceinline__ bfrag ldf(const void* p) { return *(const bfrag*)p; }
#define MFMA(a, b, c) __builtin_amdgcn_mfma_f32_32x32x16_bf16(a, b, c, 0, 0, 0)

// ------------------------------------------- edges + weight repack (merged)
// blocks 0..1919: edge bucketing (cnt pre-zeroed by hipMemsetAsync).
// blocks 1920..5407: weight repacking (independent).
// Frag-linear bf16 for MFMA A-operand, 32x32x16:
//   m/oc = oct*32 + (lane&31); k = q*16 + (lane>>5)*8 + e.
// W1f: frag = (tap*8 + q)*16 + oct ; D1f: frag = q*16 + oct
// W2f: frag = (tap*32 + q)*4 + oct ; D2f: frag = q*4 + oct
// FCWf: frag = q*3 + oct.
__global__ void k_edges_repack(
        const int* __restrict__ e32, int* __restrict__ cnt, int* __restrict__ eidx,
        const float* __restrict__ cw0, const float* __restrict__ dw0,
        const float* __restrict__ cw1, const float* __restrict__ dw1,
        const float* __restrict__ cw2, const float* __restrict__ dw2,
        const float* __restrict__ fcw,
        float* __restrict__ w0T, float* __restrict__ d0T,
        unsigned short* __restrict__ W1f, unsigned short* __restrict__ D1f,
        unsigned short* __restrict__ W2f, unsigned short* __restrict__ D2f,
        unsigned short* __restrict__ FCWf) {
    if (blockIdx.x < 1920) {
        int i = blockIdx.x * 256 + threadIdx.x;
        bool is64 = (e32[1] == 0) & (e32[3] == 0) & (e32[5] == 0) & (e32[7] == 0);
        int s, d;
        if (is64) { s = e32[2 * i]; d = e32[2 * (NEDGE + i)]; }
        else      { s = e32[i];     d = e32[NEDGE + i]; }
        int slot = atomicAdd(&cnt[d], 1);
        if (slot < MAXDEG) eidx[slot * N_NODES + d] = s;
        return;
    }
    int i = (blockIdx.x - 1920) * 256 + threadIdx.x;
    if (i < 36 * 128) { int oc = i & 127, r = i >> 7; w0T[i] = cw0[oc * 36 + r]; }
    if (i < 12 * 128) { int oc = i & 127, ic = i >> 7; d0T[i] = dw0[oc * 12 + ic]; }
    if (i < 196608) {                       // W1f
        int pos = i & 511, f = i >> 9;
        int lane = pos >> 3, e = pos & 7;
        int oct = f & 15, q = (f >> 4) & 7, tap = f >> 7;
        int oc = oct * 32 + (lane & 31), ic = q * 16 + (lane >> 5) * 8 + e;
        W1f[i] = f2bf(cw1[(oc * 128 + ic) * 3 + tap]);
    } else if (i < 262144) {                // D1f
        int j = i - 196608;
        int pos = j & 511, f = j >> 9;
        int lane = pos >> 3, e = pos & 7;
        int oct = f & 15, q = f >> 4;
        int oc = oct * 32 + (lane & 31), ic = q * 16 + (lane >> 5) * 8 + e;
        D1f[j] = f2bf(dw1[oc * 128 + ic]);
    } else if (i < 458752) {                // W2f
        int j = i - 262144;
        int pos = j & 511, f = j >> 9;
        int lane = pos >> 3, e = pos & 7;
        int oct = f & 3, q = (f >> 2) & 31, tap = f >> 7;
        int oc = oct * 32 + (lane & 31), ic = q * 16 + (lane >> 5) * 8 + e;
        W2f[j] = f2bf(cw2[(oc * 512 + ic) * 3 + tap]);
    } else if (i < 524288) {                // D2f
        int j = i - 458752;
        int pos = j & 511, f = j >> 9;
        int lane = pos >> 3, e = pos & 7;
        int oct = f & 3, q = f >> 2;
        int oc = oct * 32 + (lane & 31), ic = q * 16 + (lane >> 5) * 8 + e;
        D2f[j] = f2bf(dw2[oc * 512 + ic]);
    } else if (i < 892928) {                // FCWf (240*3 frags)
        int j = i - 524288;
        int pos = j & 511, f = j >> 9;
        int lane = pos >> 3, e = pos & 7;
        int oct = f % 3, q = f / 3;
        int o = oct * 32 + (lane & 31);
        int k = q * 16 + (lane >> 5) * 8 + e;
        float v = (o < 72) ? fcw[o * 3840 + (k & 127) * 30 + (k >> 7)] : 0.f;
        FCWf[j] = f2bf(v);
    }
}

// ----------------------------------------------------------------- gather
// GCN linearity: a[d] = sum_{s in bucket[d]} dinv[s] * x[s]  (raw features).
// The GCN 12x12 matmul + self-loop + bias are applied later in k_block0.
// 3 threads per node, 4 channels each (720 blocks).
__global__ void k_gather(const int* __restrict__ cnt, const int* __restrict__ eidx,
                         const float* __restrict__ x, float* __restrict__ a) {
    int part = blockIdx.x / 240;
    int d = (blockIdx.x - part * 240) * 256 + threadIdx.x;
    int n = cnt[d];
    if (n > MAXDEG) n = MAXDEG;
    float4 acc = make_float4(0.f, 0.f, 0.f, 0.f);
    for (int j = 0; j < n; j++) {
        int s = eidx[j * N_NODES + d];           // coalesced across lanes
        float di = rsqrtf(1.0f + (float)cnt[s]); // cnt is L2-hot (240 KB)
        float4 h = *(const float4*)(x + (size_t)s * 12 + part * 4);
        acc.x += di * h.x; acc.y += di * h.y; acc.z += di * h.z; acc.w += di * h.w;
    }
    *(float4*)(a + (size_t)d * 12 + part * 4) = acc;
}

// ------------------------------------------------------------ TCN block 0
// GCN finalize (g = (dinv*a + dinv^2*x) W^T + gb) fused into staging, then
// 12 -> 128 conv k=3 dil=1 + 1x1 down. 4 batch/WG, LDS-staged bf16 output.
__global__ __launch_bounds__(256) void k_block0(
        const float* __restrict__ x, const float* __restrict__ a,
        const int* __restrict__ cnt,
        const float* __restrict__ gw, const float* __restrict__ gb,
        const float* __restrict__ w0T, const float* __restrict__ d0T,
        const float* __restrict__ cb0, const float* __restrict__ db0,
        unsigned short* __restrict__ X1b) {
    __shared__ float wl[36 * 128];
    __shared__ float dl[12 * 128];
    __shared__ float cbl[128], dbl[128];
    __shared__ float gwl[144], gbl[12];
    __shared__ float x0[4 * TT * 12];   // g values per node
    __shared__ __align__(16) unsigned short st[2][TT * 136];
    int tid = threadIdx.x;
    int b0 = blockIdx.x * 4;
    for (int i = tid; i < 36 * 128; i += 256) wl[i] = w0T[i];
    for (int i = tid; i < 12 * 128; i += 256) dl[i] = d0T[i];
    if (tid < 128) { cbl[tid] = cb0[tid]; dbl[tid] = db0[tid]; }
    if (tid < 144) gwl[tid] = gw[tid];
    if (tid >= 144 && tid < 156) gbl[tid - 144] = gb[tid - 144];
    __syncthreads();
    if (tid < 120) {
        size_t n = (size_t)b0 * TT + tid;
        float di = rsqrtf(1.0f + (float)cnt[n]);
        float d2 = di * di;
        const float4* ap = (const float4*)(a + n * 12);
        const float4* xp = (const float4*)(x + n * 12);
        float u[12];
        #pragma unroll
        for (int q = 0; q < 3; q++) {
            float4 av = ap[q], xv = xp[q];
            u[q*4+0] = di * av.x + d2 * xv.x;
            u[q*4+1] = di * av.y + d2 * xv.y;
            u[q*4+2] = di * av.z + d2 * xv.z;
            u[q*4+3] = di * av.w + d2 * xv.w;
        }
        #pragma unroll
        for (int c = 0; c < 12; c++) {
            float acc = gbl[c];
            #pragma unroll
            for (int j = 0; j < 12; j++) acc += u[j] * gwl[c * 12 + j];
            x0[tid * 12 + c] = acc;
        }
    }
    __syncthreads();
    int oc = tid & 127, half = tid >> 7;
    float cb = cbl[oc], db = dbl[oc];
    for (int bi = 0; bi < 2; bi++) {
        int bl = bi * 2 + half;
        const float* xb = x0 + bl * (TT * 12);
        float conv[TT], res[TT];
        #pragma unroll
        for (int t = 0; t < TT; t++) { conv[t] = 0.f; res[t] = 0.f; }
        #pragma unroll
        for (int ic = 0; ic < 12; ic++) {
            float w0v = wl[(ic * 3 + 0) * 128 + oc];
            float w1v = wl[(ic * 3 + 1) * 128 + oc];
            float w2v = wl[(ic * 3 + 2) * 128 + oc];
            float dv  = dl[ic * 128 + oc];
            #pragma unroll
            for (int t = 0; t < TT; t++) {
                float xv = xb[t * 12 + ic];
                conv[t] += w2v * xv;
                if (t + 1 < TT) conv[t + 1] += w1v * xv;
                if (t + 2 < TT) conv[t + 2] += w0v * xv;
                res[t] += dv * xv;
            }
        }
        #pragma unroll
        for (int t = 0; t < TT; t++) {
            float o1 = fmaxf(conv[t] + cb, 0.f);
            st[half][t * 136 + oc] = f2bf(fmaxf(o1 + res[t] + db, 0.f));
        }
        __syncthreads();
        for (int idx = tid; idx < 2 * TT * 16; idx += 256) {
            int h = idx / (TT * 16), rem = idx - h * (TT * 16);
            int row = rem >> 4, seg = rem & 15;
            *(uint4*)(X1b + (size_t)((b0 + bi * 2 + h) * TT + row) * 128 + seg * 8) =
                *(const uint4*)(&st[h][row * 136 + seg * 8]);
        }
        __syncthreads();
    }
}

// -------------------------------------------------- TCN blocks 1+2, MFMA
// Proven round-5 structure: 2 batch/WG, 256 thr, dbuf weights, 80 KB LDS.
__global__ __launch_bounds__(256, 2) void k_tcn12(
        const unsigned short* __restrict__ X1b,
        const unsigned short* __restrict__ W1f, const unsigned short* __restrict__ D1f,
        const float* __restrict__ cb1, const float* __restrict__ db1,
        const unsigned short* __restrict__ W2f, const unsigned short* __restrict__ D2f,
        const float* __restrict__ cb2, const float* __restrict__ db2,
        unsigned short* __restrict__ X3b) {
    __shared__ __align__(16) unsigned short X1l[61 * 136];  // rows 0..59 data, 60 = zeros
    __shared__ __align__(16) unsigned short X2l[61 * 520];
    const int tid  = threadIdx.x;
    const int lane = tid & 63;
    const int wave = tid >> 6;
    const int tcol = lane & 31;
    const int half = lane >> 5;
    const int b0 = blockIdx.x * 2;

    auto ldw1 = [&](bfrag* dst, int oct, int qc) {
        #pragma unroll
        for (int tap = 0; tap < 3; tap++)
            #pragma unroll
            for (int qq = 0; qq < 4; qq++)
                dst[tap * 4 + qq] =
                    ldf(W1f + (((tap * 8 + qc * 4 + qq) * 16 + oct) << 9) + lane * 8);
        #pragma unroll
        for (int qq = 0; qq < 4; qq++)
            dst[12 + qq] = ldf(D1f + (((qc * 4 + qq) * 16 + oct) << 9) + lane * 8);
    };
    auto ldw2 = [&](bfrag* dst, int oct, int qc) {
        #pragma unroll
        for (int tap = 0; tap < 3; tap++)
            #pragma unroll
            for (int qq = 0; qq < 4; qq++)
                dst[tap * 4 + qq] =
                    ldf(W2f + (((tap * 32 + qc * 4 + qq) * 4 + oct) << 9) + lane * 8);
        #pragma unroll
        for (int qq = 0; qq < 4; qq++)
            dst[12 + qq] = ldf(D2f + (((qc * 4 + qq) * 4 + oct) << 9) + lane * 8);
    };

    for (int idx = tid; idx < 960; idx += 256) {
        int row = idx >> 4, seg = idx & 15;
        *(uint4*)(X1l + row * 136 + seg * 8) =
            *(const uint4*)(X1b + ((size_t)(b0 * 30 + row) << 7) + seg * 8);
    }
    if (tid < 17) *(uint4*)(X1l + 60 * 136 + tid * 8) = make_uint4(0, 0, 0, 0);
    if (tid < 65) *(uint4*)(X2l + 60 * 520 + tid * 8) = make_uint4(0, 0, 0, 0);
    __syncthreads();

    // ---- phase 1: block1 (128->512, k=3 dil=3) + 1x1 down  -> X2l (bf16)
    {
        bfrag wf[2][16];
        ldw1(wf[0], wave, 0);
        floatx16 accc[2], accd[2];
        #pragma unroll
        for (int s = 0; s < 8; s++) {
            const int qc = s & 1;
            const int oct = (s >> 1) * 4 + wave;
            if (qc == 0) { accc[0] = 0; accc[1] = 0; accd[0] = 0; accd[1] = 0; }
            if (s < 7)
                ldw1(wf[(s + 1) & 1], ((s + 1) >> 1) * 4 + wave, (s + 1) & 1);
            #pragma unroll
            for (int bl = 0; bl < 2; bl++) {
                bfrag bx[3][4];
                #pragma unroll
                for (int si = 0; si < 3; si++) {
                    int trow = tcol - si * 3;
                    const unsigned short* rp = ((unsigned)trow < 30u)
                        ? (X1l + (bl * 30 + trow) * 136) : (X1l + 60 * 136);
                    #pragma unroll
                    for (int qq = 0; qq < 4; qq++)
                        bx[si][qq] = ldf(rp + (qc * 4 + qq) * 16 + half * 8);
                }
                #pragma unroll
                for (int qq = 0; qq < 4; qq++) {
                    accc[bl] = MFMA(wf[s & 1][8 + qq],  bx[0][qq], accc[bl]);
                    accc[bl] = MFMA(wf[s & 1][4 + qq],  bx[1][qq], accc[bl]);
                    accc[bl] = MFMA(wf[s & 1][qq],      bx[2][qq], accc[bl]);
                    accd[bl] = MFMA(wf[s & 1][12 + qq], bx[0][qq], accd[bl]);
                }
            }
            if (qc == 1 && tcol < 30) {
                #pragma unroll
                for (int bl = 0; bl < 2; bl++) {
                    unsigned short* wp = X2l + (bl * 30 + tcol) * 520 + oct * 32 + half * 4;
                    #pragma unroll
                    for (int gi = 0; gi < 4; gi++) {
                        int ocb = oct * 32 + half * 4 + gi * 8;
                        float4 cbv = *(const float4*)(cb1 + ocb);
                        float4 dbv = *(const float4*)(db1 + ocb);
                        float v0 = fmaxf(fmaxf(accc[bl][gi*4+0] + cbv.x, 0.f) + accd[bl][gi*4+0] + dbv.x, 0.f);
                        float v1 = fmaxf(fmaxf(accc[bl][gi*4+1] + cbv.y, 0.f) + accd[bl][gi*4+1] + dbv.y, 0.f);
                        float v2 = fmaxf(fmaxf(accc[bl][gi*4+2] + cbv.z, 0.f) + accd[bl][gi*4+2] + dbv.z, 0.f);
                        float v3 = fmaxf(fmaxf(accc[bl][gi*4+3] + cbv.w, 0.f) + accd[bl][gi*4+3] + dbv.w, 0.f);
                        unsigned p0 = (unsigned)f2bf(v0) | ((unsigned)f2bf(v1) << 16);
                        unsigned p1 = (unsigned)f2bf(v2) | ((unsigned)f2bf(v3) << 16);
                        *(uint2*)(wp + gi * 8) = make_uint2(p0, p1);
                    }
                }
            }
        }
    }
    __syncthreads();

    // ---- phase 2: block2 (512->128, k=3 dil=9) + 1x1 down -> staged X3
    {
        const int oct = wave;
        bfrag wf[2][16];
        ldw2(wf[0], oct, 0);
        floatx16 accc[2], accd[2];
        accc[0] = 0; accc[1] = 0; accd[0] = 0; accd[1] = 0;
        #pragma unroll
        for (int qc = 0; qc < 8; qc++) {
            if (qc < 7) ldw2(wf[(qc + 1) & 1], oct, qc + 1);
            #pragma unroll
            for (int bl = 0; bl < 2; bl++) {
                bfrag bx[3][4];
                #pragma unroll
                for (int si = 0; si < 3; si++) {
                    int trow = tcol - si * 9;
                    const unsigned short* rp = ((unsigned)trow < 30u)
                        ? (X2l + (bl * 30 + trow) * 520) : (X2l + 60 * 520);
                    #pragma unroll
                    for (int qq = 0; qq < 4; qq++)
                        bx[si][qq] = ldf(rp + (qc * 4 + qq) * 16 + half * 8);
                }
                #pragma unroll
                for (int qq = 0; qq < 4; qq++) {
                    accc[bl] = MFMA(wf[qc & 1][8 + qq],  bx[0][qq], accc[bl]);
                    accc[bl] = MFMA(wf[qc & 1][4 + qq],  bx[1][qq], accc[bl]);
                    accc[bl] = MFMA(wf[qc & 1][qq],      bx[2][qq], accc[bl]);
                    accd[bl] = MFMA(wf[qc & 1][12 + qq], bx[0][qq], accd[bl]);
                }
            }
        }
        if (tcol < 30) {   // stage into X1l area (free after phase 1)
            #pragma unroll
            for (int bl = 0; bl < 2; bl++) {
                unsigned short* wp = X1l + (bl * 30 + tcol) * 136 + oct * 32 + half * 4;
                #pragma unroll
                for (int gi = 0; gi < 4; gi++) {
                    int ocb = oct * 32 + half * 4 + gi * 8;
                    float4 cbv = *(const float4*)(cb2 + ocb);
                    float4 dbv = *(const float4*)(db2 + ocb);
                    float v0 = fmaxf(fmaxf(accc[bl][gi*4+0] + cbv.x, 0.f) + accd[bl][gi*4+0] + dbv.x, 0.f);
                    float v1 = fmaxf(fmaxf(accc[bl][gi*4+1] + cbv.y, 0.f) + accd[bl][gi*4+1] + dbv.y, 0.f);
                    float v2 = fmaxf(fmaxf(accc[bl][gi*4+2] + cbv.z, 0.f) + accd[bl][gi*4+2] + dbv.z, 0.f);
                    float v3 = fmaxf(fmaxf(accc[bl][gi*4+3] + cbv.w, 0.f) + accd[bl][gi*4+3] + dbv.w, 0.f);
                    unsigned p0 = (unsigned)f2bf(v0) | ((unsigned)f2bf(v1) << 16);
                    unsigned p1 = (unsigned)f2bf(v2) | ((unsigned)f2bf(v3) << 16);
                    *(uint2*)(wp + gi * 8) = make_uint2(p0, p1);
                }
            }
        }
    }
    __syncthreads();
    // coalesced flush: 60 rows x 256 B contiguous
    for (int idx = tid; idx < 960; idx += 256) {
        int row = idx >> 4, seg = idx & 15;
        *(uint4*)(X3b + ((size_t)(b0 * 30 + row) << 7) + seg * 8) =
            *(const uint4*)(X1l + row * 136 + seg * 8);
    }
}

// ------------------------------------------------------------- FC (MFMA)
// B-operand staged through LDS. P layout [kc][o(96)][b(2048)].
__global__ __launch_bounds__(256) void k_fc_mfma(
        const unsigned short* __restrict__ X3b,
        const unsigned short* __restrict__ FCWf,
        float* __restrict__ P) {
    __shared__ __align__(16) unsigned short xt[128 * 248];   // 240 used + 8 pad
    const int tid  = threadIdx.x;
    const int lane = tid & 63;
    const int wave = tid >> 6;
    const int half = lane >> 5;
    const int bg = blockIdx.x & 15;
    const int kc = blockIdx.x >> 4;

    for (int idx = tid; idx < 128 * 32; idx += 256) {
        int row = idx >> 5, seg = idx & 31;
        if (seg < 30)
            *(uint4*)(xt + row * 248 + seg * 8) =
                *(const uint4*)(X3b + (size_t)(bg * 128 + row) * FCK + kc * 240 + seg * 8);
    }
    __syncthreads();

    const int bl = wave * 32 + (lane & 31);
    floatx16 acc[3];
    acc[0] = 0; acc[1] = 0; acc[2] = 0;
    #pragma unroll
    for (int ql = 0; ql < 15; ql++) {
        int q = kc * 15 + ql;
        bfrag bx = ldf(xt + bl * 248 + ql * 16 + half * 8);
        #pragma unroll
        for (int oct = 0; oct < 3; oct++) {
            bfrag af = ldf(FCWf + ((q * 3 + oct) << 9) + lane * 8);
            acc[oct] = MFMA(af, bx, acc[oct]);
        }
    }
    float* base = P + (size_t)kc * 96 * BATCH;
    const int b = bg * 128 + bl;
    #pragma unroll
    for (int oct = 0; oct < 3; oct++)
        #pragma unroll
        for (int j = 0; j < 16; j++) {
            int o = oct * 32 + half * 4 + (j >> 2) * 8 + (j & 3);
            base[(size_t)o * BATCH + b] = acc[oct][j];
        }
}

__global__ __launch_bounds__(256) void k_fc_reduce(
        const float* __restrict__ P, const float* __restrict__ fcb,
        float* __restrict__ out) {
    int j = blockIdx.x * blockDim.x + threadIdx.x;   // j = o*2048 + b, o<72
    int o = j >> 11, b = j & 2047;
    float acc = fcb[o];
    #pragma unroll
    for (int kc = 0; kc < 16; kc++)
        acc += P[((size_t)kc * 96 + o) * BATCH + b];
    out[b * 72 + o] = acc;
}

// ---------------------------------------------------------------- launch

extern "C" void kernel_launch(void* const* d_in, const int* in_sizes, int n_in,
                              void* d_out, int out_size, void* d_ws, size_t ws_size,
                              hipStream_t stream) {
    const float* x   = (const float*)d_in[0];
    const int*   e32 = (const int*)  d_in[1];
    const float* gw  = (const float*)d_in[2];
    const float* gb  = (const float*)d_in[3];
    const float* cw0 = (const float*)d_in[4];
    const float* cb0 = (const float*)d_in[5];
    const float* dw0 = (const float*)d_in[6];
    const float* db0 = (const float*)d_in[7];
    const float* cw1 = (const float*)d_in[8];
    const float* cb1 = (const float*)d_in[9];
    const float* dw1 = (const float*)d_in[10];
    const float* db1 = (const float*)d_in[11];
    const float* cw2 = (const float*)d_in[12];
    const float* cb2 = (const float*)d_in[13];
    const float* dw2 = (const float*)d_in[14];
    const float* db2 = (const float*)d_in[15];
    const float* fcw = (const float*)d_in[16];
    const float* fcb = (const float*)d_in[17];

    char* w = (char*)d_ws;
    auto alloc = [&](size_t bytes) {
        char* p = w;
        w += (bytes + 255) & ~(size_t)255;
        return p;
    };
    int*   cnt  = (int*)  alloc(N_NODES * 4);
    int*   eidx = (int*)  alloc((size_t)N_NODES * MAXDEG * 4);
    float* a    = (float*)alloc((size_t)N_NODES * 12 * 4);
    float* w0T  = (float*)alloc(36 * 128 * 4);
    float* d0T  = (float*)alloc(12 * 128 * 4);
    unsigned short* W1f  = (unsigned short*)alloc(196608 * 2);
    unsigned short* D1f  = (unsigned short*)alloc(65536 * 2);
    unsigned short* W2f  = (unsigned short*)alloc(196608 * 2);
    unsigned short* D2f  = (unsigned short*)alloc(65536 * 2);
    unsigned short* FCWf = (unsigned short*)alloc(368640 * 2);
    unsigned short* X1b  = (unsigned short*)alloc((size_t)BATCH * TT * C1 * 2);
    unsigned short* X3b  = (unsigned short*)alloc((size_t)BATCH * TT * C3 * 2);
    float* P    = (float*)alloc((size_t)16 * 96 * BATCH * 4);

    hipMemsetAsync(cnt, 0, N_NODES * 4, stream);
    k_edges_repack<<<1920 + 3488, 256, 0, stream>>>(
        e32, cnt, eidx, cw0, dw0, cw1, dw1, cw2, dw2, fcw,
        w0T, d0T, W1f, D1f, W2f, D2f, FCWf);
    k_gather<<<720, 256, 0, stream>>>(cnt, eidx, x, a);
    k_block0<<<BATCH / 4, 256, 0, stream>>>(x, a, cnt, gw, gb,
                                            w0T, d0T, cb0, db0, X1b);
    k_tcn12<<<BATCH / 2, 256, 0, stream>>>(X1b, W1f, D1f, cb1, db1,
                                           W2f, D2f, cb2, db2, X3b);
    k_fc_mfma<<<256, 256, 0, stream>>>(X3b, FCWf, P);
    k_fc_reduce<<<72 * BATCH / 256, 256, 0, stream>>>(P, fcb, (float*)d_out);
}

// Round 10
// 235.666 us; speedup vs baseline: 1.5153x; 1.0414x over previous
//
#include <hip/hip_runtime.h>
#include <hip/hip_bf16.h>

#define N_NODES 61440
#define NEDGE   491520
#define BATCH   2048
#define TT      30
#define C1      128
#define C2      512
#define C3      128
#define FCK     3840   // 128*30
#define MAXDEG  40     // Poisson(8) tail: P(deg>40) ~ 1e-11

typedef float floatx16 __attribute__((ext_vector_type(16)));
typedef __bf16 bfrag   __attribute__((ext_vector_type(8)));

static __device__ __forceinline__ unsigned short f2bf(float f) {
    unsigned u = __float_as_uint(f);
    u = u + 0x7fffu + ((u >> 16) & 1u);
    return (unsigned short)(u >> 16);
}
static __device__ __forceinline__ bfrag ldf(const void* p) { return *(const bfrag*)p; }
#define MFMA(a, b, c) __builtin_amdgcn_mfma_f32_32x32x16_bf16(a, b, c, 0, 0, 0)

// ------------------------------------------- edges + weight repack (merged)
// blocks 0..1919: edge bucketing (cnt pre-zeroed by hipMemsetAsync).
//   eidx is ushort [slot][node] (node ids < 2^16): halves scatter footprint.
// blocks 1920..5407: weight repacking (independent).
__global__ void k_edges_repack(
        const int* __restrict__ e32, int* __restrict__ cnt,
        unsigned short* __restrict__ eidx,
        const float* __restrict__ cw0, const float* __restrict__ dw0,
        const float* __restrict__ cw1, const float* __restrict__ dw1,
        const float* __restrict__ cw2, const float* __restrict__ dw2,
        const float* __restrict__ fcw,
        float* __restrict__ w0T, float* __restrict__ d0T,
        unsigned short* __restrict__ W1f, unsigned short* __restrict__ D1f,
        unsigned short* __restrict__ W2f, unsigned short* __restrict__ D2f,
        unsigned short* __restrict__ FCWf) {
    if (blockIdx.x < 1920) {
        int i = blockIdx.x * 256 + threadIdx.x;
        bool is64 = (e32[1] == 0) & (e32[3] == 0) & (e32[5] == 0) & (e32[7] == 0);
        int s, d;
        if (is64) { s = e32[2 * i]; d = e32[2 * (NEDGE + i)]; }
        else      { s = e32[i];     d = e32[NEDGE + i]; }
        int slot = atomicAdd(&cnt[d], 1);
        if (slot < MAXDEG) eidx[slot * N_NODES + d] = (unsigned short)s;
        return;
    }
    int i = (blockIdx.x - 1920) * 256 + threadIdx.x;
    if (i < 36 * 128) { int oc = i & 127, r = i >> 7; w0T[i] = cw0[oc * 36 + r]; }
    if (i < 12 * 128) { int oc = i & 127, ic = i >> 7; d0T[i] = dw0[oc * 12 + ic]; }
    if (i < 196608) {                       // W1f
        int pos = i & 511, f = i >> 9;
        int lane = pos >> 3, e = pos & 7;
        int oct = f & 15, q = (f >> 4) & 7, tap = f >> 7;
        int oc = oct * 32 + (lane & 31), ic = q * 16 + (lane >> 5) * 8 + e;
        W1f[i] = f2bf(cw1[(oc * 128 + ic) * 3 + tap]);
    } else if (i < 262144) {                // D1f
        int j = i - 196608;
        int pos = j & 511, f = j >> 9;
        int lane = pos >> 3, e = pos & 7;
        int oct = f & 15, q = f >> 4;
        int oc = oct * 32 + (lane & 31), ic = q * 16 + (lane >> 5) * 8 + e;
        D1f[j] = f2bf(dw1[oc * 128 + ic]);
    } else if (i < 458752) {                // W2f
        int j = i - 262144;
        int pos = j & 511, f = j >> 9;
        int lane = pos >> 3, e = pos & 7;
        int oct = f & 3, q = (f >> 2) & 31, tap = f >> 7;
        int oc = oct * 32 + (lane & 31), ic = q * 16 + (lane >> 5) * 8 + e;
        W2f[j] = f2bf(cw2[(oc * 512 + ic) * 3 + tap]);
    } else if (i < 524288) {                // D2f
        int j = i - 458752;
        int pos = j & 511, f = j >> 9;
        int lane = pos >> 3, e = pos & 7;
        int oct = f & 3, q = f >> 2;
        int oc = oct * 32 + (lane & 31), ic = q * 16 + (lane >> 5) * 8 + e;
        D2f[j] = f2bf(dw2[oc * 512 + ic]);
    } else if (i < 892928) {                // FCWf (240*3 frags)
        int j = i - 524288;
        int pos = j & 511, f = j >> 9;
        int lane = pos >> 3, e = pos & 7;
        int oct = f % 3, q = f / 3;
        int o = oct * 32 + (lane & 31);
        int k = q * 16 + (lane >> 5) * 8 + e;
        float v = (o < 72) ? fcw[o * 3840 + (k & 127) * 30 + (k >> 7)] : 0.f;
        FCWf[j] = f2bf(v);
    }
}

// ------------------------------------------------------------ TCN block 0
// Fused: edge gather (GCN linearity: a = sum dinv[s]*x[s]) + GCN finalize
// (g = (dinv*a + dinv^2*x) W^T + gb) + conv 12->128 k=3 dil=1 + 1x1 down.
// 4 batch/WG. Gather split: threads 0-119 ch0-5, threads 128-247 ch6-11.
__global__ __launch_bounds__(256) void k_block0(
        const float* __restrict__ x, const int* __restrict__ cnt,
        const unsigned short* __restrict__ eidx,
        const float* __restrict__ gw, const float* __restrict__ gb,
        const float* __restrict__ w0T, const float* __restrict__ d0T,
        const float* __restrict__ cb0, const float* __restrict__ db0,
        unsigned short* __restrict__ X1b) {
    __shared__ float wl[36 * 128];
    __shared__ float dl[12 * 128];
    __shared__ float cbl[128], dbl[128];
    __shared__ float gwl[144], gbl[12];
    __shared__ float aL[120][12];
    __shared__ float x0[4 * TT * 12];   // g values per node
    __shared__ __align__(16) unsigned short st[2][TT * 136];
    int tid = threadIdx.x;
    int b0 = blockIdx.x * 4;
    for (int i = tid; i < 36 * 128; i += 256) wl[i] = w0T[i];
    for (int i = tid; i < 12 * 128; i += 256) dl[i] = d0T[i];
    if (tid < 128) { cbl[tid] = cb0[tid]; dbl[tid] = db0[tid]; }
    if (tid < 144) gwl[tid] = gw[tid];
    if (tid >= 144 && tid < 156) gbl[tid - 144] = gb[tid - 144];

    // ---- gather: neighbor aggregation, 6 channels per thread half
    {
        int th = tid & 127;
        int grp = tid >> 7;
        if (th < 120) {
            size_t n = (size_t)b0 * TT + th;
            int ne = cnt[n]; if (ne > MAXDEG) ne = MAXDEG;
            float a0 = 0.f, a1 = 0.f, a2 = 0.f, a3 = 0.f, a4 = 0.f, a5 = 0.f;
            for (int j = 0; j < ne; j++) {
                int s = eidx[j * N_NODES + n];        // coalesced across th
                float di = rsqrtf(1.0f + (float)cnt[s]);
                const float2* xp = (const float2*)(x + (size_t)s * 12 + grp * 6);
                float2 p0 = xp[0], p1 = xp[1], p2 = xp[2];
                a0 += di * p0.x; a1 += di * p0.y;
                a2 += di * p1.x; a3 += di * p1.y;
                a4 += di * p2.x; a5 += di * p2.y;
            }
            float* ap = &aL[th][grp * 6];
            ap[0] = a0; ap[1] = a1; ap[2] = a2; ap[3] = a3; ap[4] = a4; ap[5] = a5;
        }
    }
    __syncthreads();

    // ---- GCN finalize: u = dinv*a + dinv^2*x ; g = u gw^T + gb
    if (tid < 120) {
        size_t n = (size_t)b0 * TT + tid;
        float di = rsqrtf(1.0f + (float)cnt[n]);
        float d2 = di * di;
        const float4* xp = (const float4*)(x + n * 12);
        float u[12];
        #pragma unroll
        for (int q = 0; q < 3; q++) {
            float4 xv = xp[q];
            u[q*4+0] = di * aL[tid][q*4+0] + d2 * xv.x;
            u[q*4+1] = di * aL[tid][q*4+1] + d2 * xv.y;
            u[q*4+2] = di * aL[tid][q*4+2] + d2 * xv.z;
            u[q*4+3] = di * aL[tid][q*4+3] + d2 * xv.w;
        }
        #pragma unroll
        for (int c = 0; c < 12; c++) {
            float acc = gbl[c];
            #pragma unroll
            for (int j = 0; j < 12; j++) acc += u[j] * gwl[c * 12 + j];
            x0[tid * 12 + c] = acc;
        }
    }
    __syncthreads();

    // ---- conv 12->128 + down, per-thread over t
    int oc = tid & 127, half = tid >> 7;
    float cb = cbl[oc], db = dbl[oc];
    for (int bi = 0; bi < 2; bi++) {
        int bl = bi * 2 + half;
        const float* xb = x0 + bl * (TT * 12);
        float conv[TT], res[TT];
        #pragma unroll
        for (int t = 0; t < TT; t++) { conv[t] = 0.f; res[t] = 0.f; }
        #pragma unroll
        for (int ic = 0; ic < 12; ic++) {
            float w0v = wl[(ic * 3 + 0) * 128 + oc];
            float w1v = wl[(ic * 3 + 1) * 128 + oc];
            float w2v = wl[(ic * 3 + 2) * 128 + oc];
            float dv  = dl[ic * 128 + oc];
            #pragma unroll
            for (int t = 0; t < TT; t++) {
                float xv = xb[t * 12 + ic];
                conv[t] += w2v * xv;
                if (t + 1 < TT) conv[t + 1] += w1v * xv;
                if (t + 2 < TT) conv[t + 2] += w0v * xv;
                res[t] += dv * xv;
            }
        }
        #pragma unroll
        for (int t = 0; t < TT; t++) {
            float o1 = fmaxf(conv[t] + cb, 0.f);
            st[half][t * 136 + oc] = f2bf(fmaxf(o1 + res[t] + db, 0.f));
        }
        __syncthreads();
        for (int idx = tid; idx < 2 * TT * 16; idx += 256) {
            int h = idx / (TT * 16), rem = idx - h * (TT * 16);
            int row = rem >> 4, seg = rem & 15;
            *(uint4*)(X1b + (size_t)((b0 + bi * 2 + h) * TT + row) * 128 + seg * 8) =
                *(const uint4*)(&st[h][row * 136 + seg * 8]);
        }
        __syncthreads();
    }
}

// -------------------------------------------------- TCN blocks 1+2, MFMA
// Proven round-5 structure: 2 batch/WG, 256 thr, dbuf weights, 80 KB LDS.
__global__ __launch_bounds__(256, 2) void k_tcn12(
        const unsigned short* __restrict__ X1b,
        const unsigned short* __restrict__ W1f, const unsigned short* __restrict__ D1f,
        const float* __restrict__ cb1, const float* __restrict__ db1,
        const unsigned short* __restrict__ W2f, const unsigned short* __restrict__ D2f,
        const float* __restrict__ cb2, const float* __restrict__ db2,
        unsigned short* __restrict__ X3b) {
    __shared__ __align__(16) unsigned short X1l[61 * 136];  // rows 0..59 data, 60 = zeros
    __shared__ __align__(16) unsigned short X2l[61 * 520];
    const int tid  = threadIdx.x;
    const int lane = tid & 63;
    const int wave = tid >> 6;
    const int tcol = lane & 31;
    const int half = lane >> 5;
    const int b0 = blockIdx.x * 2;

    auto ldw1 = [&](bfrag* dst, int oct, int qc) {
        #pragma unroll
        for (int tap = 0; tap < 3; tap++)
            #pragma unroll
            for (int qq = 0; qq < 4; qq++)
                dst[tap * 4 + qq] =
                    ldf(W1f + (((tap * 8 + qc * 4 + qq) * 16 + oct) << 9) + lane * 8);
        #pragma unroll
        for (int qq = 0; qq < 4; qq++)
            dst[12 + qq] = ldf(D1f + (((qc * 4 + qq) * 16 + oct) << 9) + lane * 8);
    };
    auto ldw2 = [&](bfrag* dst, int oct, int qc) {
        #pragma unroll
        for (int tap = 0; tap < 3; tap++)
            #pragma unroll
            for (int qq = 0; qq < 4; qq++)
                dst[tap * 4 + qq] =
                    ldf(W2f + (((tap * 32 + qc * 4 + qq) * 4 + oct) << 9) + lane * 8);
        #pragma unroll
        for (int qq = 0; qq < 4; qq++)
            dst[12 + qq] = ldf(D2f + (((qc * 4 + qq) * 4 + oct) << 9) + lane * 8);
    };

    for (int idx = tid; idx < 960; idx += 256) {
        int row = idx >> 4, seg = idx & 15;
        *(uint4*)(X1l + row * 136 + seg * 8) =
            *(const uint4*)(X1b + ((size_t)(b0 * 30 + row) << 7) + seg * 8);
    }
    if (tid < 17) *(uint4*)(X1l + 60 * 136 + tid * 8) = make_uint4(0, 0, 0, 0);
    if (tid < 65) *(uint4*)(X2l + 60 * 520 + tid * 8) = make_uint4(0, 0, 0, 0);
    __syncthreads();

    // ---- phase 1: block1 (128->512, k=3 dil=3) + 1x1 down  -> X2l (bf16)
    {
        bfrag wf[2][16];
        ldw1(wf[0], wave, 0);
        floatx16 accc[2], accd[2];
        #pragma unroll
        for (int s = 0; s < 8; s++) {
            const int qc = s & 1;
            const int oct = (s >> 1) * 4 + wave;
            if (qc == 0) { accc[0] = 0; accc[1] = 0; accd[0] = 0; accd[1] = 0; }
            if (s < 7)
                ldw1(wf[(s + 1) & 1], ((s + 1) >> 1) * 4 + wave, (s + 1) & 1);
            #pragma unroll
            for (int bl = 0; bl < 2; bl++) {
                bfrag bx[3][4];
                #pragma unroll
                for (int si = 0; si < 3; si++) {
                    int trow = tcol - si * 3;
                    const unsigned short* rp = ((unsigned)trow < 30u)
                        ? (X1l + (bl * 30 + trow) * 136) : (X1l + 60 * 136);
                    #pragma unroll
                    for (int qq = 0; qq < 4; qq++)
                        bx[si][qq] = ldf(rp + (qc * 4 + qq) * 16 + half * 8);
                }
                #pragma unroll
                for (int qq = 0; qq < 4; qq++) {
                    accc[bl] = MFMA(wf[s & 1][8 + qq],  bx[0][qq], accc[bl]);
                    accc[bl] = MFMA(wf[s & 1][4 + qq],  bx[1][qq], accc[bl]);
                    accc[bl] = MFMA(wf[s & 1][qq],      bx[2][qq], accc[bl]);
                    accd[bl] = MFMA(wf[s & 1][12 + qq], bx[0][qq], accd[bl]);
                }
            }
            if (qc == 1 && tcol < 30) {
                #pragma unroll
                for (int bl = 0; bl < 2; bl++) {
                    unsigned short* wp = X2l + (bl * 30 + tcol) * 520 + oct * 32 + half * 4;
                    #pragma unroll
                    for (int gi = 0; gi < 4; gi++) {
                        int ocb = oct * 32 + half * 4 + gi * 8;
                        float4 cbv = *(const float4*)(cb1 + ocb);
                        float4 dbv = *(const float4*)(db1 + ocb);
                        float v0 = fmaxf(fmaxf(accc[bl][gi*4+0] + cbv.x, 0.f) + accd[bl][gi*4+0] + dbv.x, 0.f);
                        float v1 = fmaxf(fmaxf(accc[bl][gi*4+1] + cbv.y, 0.f) + accd[bl][gi*4+1] + dbv.y, 0.f);
                        float v2 = fmaxf(fmaxf(accc[bl][gi*4+2] + cbv.z, 0.f) + accd[bl][gi*4+2] + dbv.z, 0.f);
                        float v3 = fmaxf(fmaxf(accc[bl][gi*4+3] + cbv.w, 0.f) + accd[bl][gi*4+3] + dbv.w, 0.f);
                        unsigned p0 = (unsigned)f2bf(v0) | ((unsigned)f2bf(v1) << 16);
                        unsigned p1 = (unsigned)f2bf(v2) | ((unsigned)f2bf(v3) << 16);
                        *(uint2*)(wp + gi * 8) = make_uint2(p0, p1);
                    }
                }
            }
        }
    }
    __syncthreads();

    // ---- phase 2: block2 (512->128, k=3 dil=9) + 1x1 down -> staged X3
    {
        const int oct = wave;
        bfrag wf[2][16];
        ldw2(wf[0], oct, 0);
        floatx16 accc[2], accd[2];
        accc[0] = 0; accc[1] = 0; accd[0] = 0; accd[1] = 0;
        #pragma unroll
        for (int qc = 0; qc < 8; qc++) {
            if (qc < 7) ldw2(wf[(qc + 1) & 1], oct, qc + 1);
            #pragma unroll
            for (int bl = 0; bl < 2; bl++) {
                bfrag bx[3][4];
                #pragma unroll
                for (int si = 0; si < 3; si++) {
                    int trow = tcol - si * 9;
                    const unsigned short* rp = ((unsigned)trow < 30u)
                        ? (X2l + (bl * 30 + trow) * 520) : (X2l + 60 * 520);
                    #pragma unroll
                    for (int qq = 0; qq < 4; qq++)
                        bx[si][qq] = ldf(rp + (qc * 4 + qq) * 16 + half * 8);
                }
                #pragma unroll
                for (int qq = 0; qq < 4; qq++) {
                    accc[bl] = MFMA(wf[qc & 1][8 + qq],  bx[0][qq], accc[bl]);
                    accc[bl] = MFMA(wf[qc & 1][4 + qq],  bx[1][qq], accc[bl]);
                    accc[bl] = MFMA(wf[qc & 1][qq],      bx[2][qq], accc[bl]);
                    accd[bl] = MFMA(wf[qc & 1][12 + qq], bx[0][qq], accd[bl]);
                }
            }
        }
        if (tcol < 30) {   // stage into X1l area (free after phase 1)
            #pragma unroll
            for (int bl = 0; bl < 2; bl++) {
                unsigned short* wp = X1l + (bl * 30 + tcol) * 136 + oct * 32 + half * 4;
                #pragma unroll
                for (int gi = 0; gi < 4; gi++) {
                    int ocb = oct * 32 + half * 4 + gi * 8;
                    float4 cbv = *(const float4*)(cb2 + ocb);
                    float4 dbv = *(const float4*)(db2 + ocb);
                    float v0 = fmaxf(fmaxf(accc[bl][gi*4+0] + cbv.x, 0.f) + accd[bl][gi*4+0] + dbv.x, 0.f);
                    float v1 = fmaxf(fmaxf(accc[bl][gi*4+1] + cbv.y, 0.f) + accd[bl][gi*4+1] + dbv.y, 0.f);
                    float v2 = fmaxf(fmaxf(accc[bl][gi*4+2] + cbv.z, 0.f) + accd[bl][gi*4+2] + dbv.z, 0.f);
                    float v3 = fmaxf(fmaxf(accc[bl][gi*4+3] + cbv.w, 0.f) + accd[bl][gi*4+3] + dbv.w, 0.f);
                    unsigned p0 = (unsigned)f2bf(v0) | ((unsigned)f2bf(v1) << 16);
                    unsigned p1 = (unsigned)f2bf(v2) | ((unsigned)f2bf(v3) << 16);
                    *(uint2*)(wp + gi * 8) = make_uint2(p0, p1);
                }
            }
        }
    }
    __syncthreads();
    // coalesced flush: 60 rows x 256 B contiguous
    for (int idx = tid; idx < 960; idx += 256) {
        int row = idx >> 4, seg = idx & 15;
        *(uint4*)(X3b + ((size_t)(b0 * 30 + row) << 7) + seg * 8) =
            *(const uint4*)(X1l + row * 136 + seg * 8);
    }
}

// ------------------------------------------------------------- FC (MFMA)
// B-operand staged through LDS. P partials bf16, layout [kc][o(96)][b(2048)].
__global__ __launch_bounds__(256) void k_fc_mfma(
        const unsigned short* __restrict__ X3b,
        const unsigned short* __restrict__ FCWf,
        unsigned short* __restrict__ P) {
    __shared__ __align__(16) unsigned short xt[128 * 248];   // 240 used + 8 pad
    const int tid  = threadIdx.x;
    const int lane = tid & 63;
    const int wave = tid >> 6;
    const int half = lane >> 5;
    const int bg = blockIdx.x & 15;
    const int kc = blockIdx.x >> 4;

    for (int idx = tid; idx < 128 * 32; idx += 256) {
        int row = idx >> 5, seg = idx & 31;
        if (seg < 30)
            *(uint4*)(xt + row * 248 + seg * 8) =
                *(const uint4*)(X3b + (size_t)(bg * 128 + row) * FCK + kc * 240 + seg * 8);
    }
    __syncthreads();

    const int bl = wave * 32 + (lane & 31);
    floatx16 acc[3];
    acc[0] = 0; acc[1] = 0; acc[2] = 0;
    #pragma unroll
    for (int ql = 0; ql < 15; ql++) {
        int q = kc * 15 + ql;
        bfrag bx = ldf(xt + bl * 248 + ql * 16 + half * 8);
        #pragma unroll
        for (int oct = 0; oct < 3; oct++) {
            bfrag af = ldf(FCWf + ((q * 3 + oct) << 9) + lane * 8);
            acc[oct] = MFMA(af, bx, acc[oct]);
        }
    }
    unsigned short* base = P + (size_t)kc * 96 * BATCH;
    const int b = bg * 128 + bl;
    #pragma unroll
    for (int oct = 0; oct < 3; oct++)
        #pragma unroll
        for (int j = 0; j < 16; j++) {
            int o = oct * 32 + half * 4 + (j >> 2) * 8 + (j & 3);
            base[(size_t)o * BATCH + b] = f2bf(acc[oct][j]);
        }
}

__global__ __launch_bounds__(256) void k_fc_reduce(
        const unsigned short* __restrict__ P, const float* __restrict__ fcb,
        float* __restrict__ out) {
    int j = blockIdx.x * blockDim.x + threadIdx.x;   // j = o*2048 + b, o<72
    int o = j >> 11, b = j & 2047;
    float acc = fcb[o];
    #pragma unroll
    for (int kc = 0; kc < 16; kc++) {
        unsigned u = P[((size_t)kc * 96 + o) * BATCH + b];
        acc += __uint_as_float(u << 16);
    }
    out[b * 72 + o] = acc;
}

// ---------------------------------------------------------------- launch

extern "C" void kernel_launch(void* const* d_in, const int* in_sizes, int n_in,
                              void* d_out, int out_size, void* d_ws, size_t ws_size,
                              hipStream_t stream) {
    const float* x   = (const float*)d_in[0];
    const int*   e32 = (const int*)  d_in[1];
    const float* gw  = (const float*)d_in[2];
    const float* gb  = (const float*)d_in[3];
    const float* cw0 = (const float*)d_in[4];
    const float* cb0 = (const float*)d_in[5];
    const float* dw0 = (const float*)d_in[6];
    const float* db0 = (const float*)d_in[7];
    const float* cw1 = (const float*)d_in[8];
    const float* cb1 = (const float*)d_in[9];
    const float* dw1 = (const float*)d_in[10];
    const float* db1 = (const float*)d_in[11];
    const float* cw2 = (const float*)d_in[12];
    const float* cb2 = (const float*)d_in[13];
    const float* dw2 = (const float*)d_in[14];
    const float* db2 = (const float*)d_in[15];
    const float* fcw = (const float*)d_in[16];
    const float* fcb = (const float*)d_in[17];

    char* w = (char*)d_ws;
    auto alloc = [&](size_t bytes) {
        char* p = w;
        w += (bytes + 255) & ~(size_t)255;
        return p;
    };
    int*            cnt  = (int*)           alloc(N_NODES * 4);
    unsigned short* eidx = (unsigned short*)alloc((size_t)N_NODES * MAXDEG * 2);
    float* w0T  = (float*)alloc(36 * 128 * 4);
    float* d0T  = (float*)alloc(12 * 128 * 4);
    unsigned short* W1f  = (unsigned short*)alloc(196608 * 2);
    unsigned short* D1f  = (unsigned short*)alloc(65536 * 2);
    unsigned short* W2f  = (unsigned short*)alloc(196608 * 2);
    unsigned short* D2f  = (unsigned short*)alloc(65536 * 2);
    unsigned short* FCWf = (unsigned short*)alloc(368640 * 2);
    unsigned short* X1b  = (unsigned short*)alloc((size_t)BATCH * TT * C1 * 2);
    unsigned short* X3b  = (unsigned short*)alloc((size_t)BATCH * TT * C3 * 2);
    unsigned short* P    = (unsigned short*)alloc((size_t)16 * 96 * BATCH * 2);

    hipMemsetAsync(cnt, 0, N_NODES * 4, stream);
    k_edges_repack<<<1920 + 3488, 256, 0, stream>>>(
        e32, cnt, eidx, cw0, dw0, cw1, dw1, cw2, dw2, fcw,
        w0T, d0T, W1f, D1f, W2f, D2f, FCWf);
    k_block0<<<BATCH / 4, 256, 0, stream>>>(x, cnt, eidx, gw, gb,
                                            w0T, d0T, cb0, db0, X1b);
    k_tcn12<<<BATCH / 2, 256, 0, stream>>>(X1b, W1f, D1f, cb1, db1,
                                           W2f, D2f, cb2, db2, X3b);
    k_fc_mfma<<<256, 256, 0, stream>>>(X3b, FCWf, P);
    k_fc_reduce<<<72 * BATCH / 256, 256, 0, stream>>>(P, fcb, (float*)d_out);
}